// Round 9
// baseline (361.951 us; speedup 1.0000x reference)
//
#include <hip/hip_runtime.h>
#include <hip/hip_fp16.h>

#define NN 50000
#define NE 1200000
#define DIM 64
#define NB 782            // node buckets of 64: ceil(50000/64)
#define SLICES 512
#define ES 2344           // ceil(NE/SLICES); 512*2344 = 1200128 >= NE
#define VCAP 2048         // vsort bucket cache cap (mean 1536, ~13 sigma)
#define GB 782            // gemm blocks: ceil(NN/64)
#define FRONT_LDS 33792   // max(lsort ~18.3KB, gemm 33.8KB, fold 32KB)
#define FB 3125           // fused agg+gemm blocks: NN/16 exactly

// ---------------- fold body (runs inside k_front's tail blocks):
// W'_i = enc_w_i @ upd_w_i, c_i = enc_b_i @ upd_w_i, d_i = c_i + upd_b_i.
__device__ __forceinline__ void fold_body(char* smem, int i,
                                          const float* __restrict__ E,
                                          const float* __restrict__ e,
                                          const float* __restrict__ U,
                                          const float* __restrict__ ub,
                                          float* __restrict__ Wp,
                                          float* __restrict__ cvec,
                                          float* __restrict__ dvec) {
    float (*Es)[64] = (float(*)[64])smem;
    float (*Us)[64] = (float(*)[64])(smem + 16384);
    int t = threadIdx.x;
#pragma unroll
    for (int j = 0; j < 4; ++j) {
        int idx = t + j * 256;
        int r = idx >> 4, c = (idx & 15) << 2;
        *(float4*)&Es[r][c] = *(const float4*)&E[r * 64 + c];
        *(float4*)&Us[r][c] = *(const float4*)&U[r * 64 + c];
    }
    __syncthreads();
    int r0 = (t >> 4) * 4;
    int c0 = (t & 15) * 4;
    float acc[4][4] = {};
#pragma unroll
    for (int k = 0; k < 64; k += 4) {
        float4 b0 = *(float4*)&Us[k + 0][c0];
        float4 b1 = *(float4*)&Us[k + 1][c0];
        float4 b2 = *(float4*)&Us[k + 2][c0];
        float4 b3 = *(float4*)&Us[k + 3][c0];
#pragma unroll
        for (int q = 0; q < 4; ++q) {
            float4 av = *(float4*)&Es[r0 + q][k];
            acc[q][0] = fmaf(av.x, b0.x, fmaf(av.y, b1.x, fmaf(av.z, b2.x, fmaf(av.w, b3.x, acc[q][0]))));
            acc[q][1] = fmaf(av.x, b0.y, fmaf(av.y, b1.y, fmaf(av.z, b2.y, fmaf(av.w, b3.y, acc[q][1]))));
            acc[q][2] = fmaf(av.x, b0.z, fmaf(av.y, b1.z, fmaf(av.z, b2.z, fmaf(av.w, b3.z, acc[q][2]))));
            acc[q][3] = fmaf(av.x, b0.w, fmaf(av.y, b1.w, fmaf(av.z, b2.w, fmaf(av.w, b3.w, acc[q][3]))));
        }
    }
    float* W = Wp + i * 4096;
#pragma unroll
    for (int q = 0; q < 4; ++q)
        *(float4*)&W[(r0 + q) * 64 + c0] = make_float4(acc[q][0], acc[q][1], acc[q][2], acc[q][3]);
    if (t < 64) {
        float sc = 0.f;
        for (int k = 0; k < 64; ++k) sc = fmaf(e[k], Us[k][t], sc);
        cvec[i * 64 + t] = sc;
        dvec[i * 64 + t] = sc + ub[t];
    }
}

// ================= fused front kernel bodies =================

// slice bucket-sort body, two passes (U for degrees, V for CSR build).
__device__ __forceinline__ void lsort_body(char* smem, const int* __restrict__ ei,
                                           ushort* __restrict__ usort,
                                           int* __restrict__ ebuf,
                                           int* __restrict__ lpart_u,
                                           int* __restrict__ lpart_v,
                                           int s) {
    int* hist = (int*)smem;                       // (NB+1)*4 -> pad 3136
    int* wsum = (int*)(smem + 3136);              // 4 ints
    ushort* sbu = (ushort*)(smem + 4160);         // ES*2 = 4688
    int* sbv = (int*)(smem + 8848);               // ES*4 = 9376 -> end 18224
    int t = threadIdx.x;
    int w = t >> 6, l = t & 63;
    int e0 = s * ES, e1 = min(e0 + ES, NE), len = e1 - e0;
    int i0 = t * 4;

    int uv[10], vv[10];
#pragma unroll
    for (int j = 0; j < 10; ++j) {
        int e = e0 + t + j * 256;
        uv[j] = (e < e1) ? ei[e] : -1;
        vv[j] = (e < e1) ? ei[NE + e] : -1;
    }

    // ======== pass U
    for (int i = t; i < NB; i += 256) hist[i] = 0;
    __syncthreads();
#pragma unroll
    for (int j = 0; j < 10; ++j)
        if (uv[j] >= 0) atomicAdd(&hist[uv[j] >> 6], 1);
    __syncthreads();
    {
        int h0 = (i0 + 0 < NB) ? hist[i0 + 0] : 0;
        int h1 = (i0 + 1 < NB) ? hist[i0 + 1] : 0;
        int h2 = (i0 + 2 < NB) ? hist[i0 + 2] : 0;
        int h3 = (i0 + 3 < NB) ? hist[i0 + 3] : 0;
        int p1 = h0, p2 = h0 + h1, p3 = p2 + h2, p4 = p3 + h3;
        int inc = p4;
        for (int o = 1; o < 64; o <<= 1) {
            int x = __shfl_up(inc, o, 64);
            if (l >= o) inc += x;
        }
        if (l == 63) wsum[w] = inc;
        __syncthreads();
        int base = 0;
#pragma unroll
        for (int j = 0; j < 4; ++j) if (j < w) base += wsum[j];
        int total = wsum[0] + wsum[1] + wsum[2] + wsum[3];
        int excl = base + inc - p4;
        int* lpu = lpart_u + s * (NB + 1);
        if (i0 + 0 < NB) { lpu[i0 + 0] = excl;      hist[i0 + 0] = excl; }
        if (i0 + 1 < NB) { lpu[i0 + 1] = excl + p1; hist[i0 + 1] = excl + p1; }
        if (i0 + 2 < NB) { lpu[i0 + 2] = excl + p2; hist[i0 + 2] = excl + p2; }
        if (i0 + 3 < NB) { lpu[i0 + 3] = excl + p3; hist[i0 + 3] = excl + p3; }
        if (t == 255) lpu[NB] = total;
    }
    __syncthreads();
#pragma unroll
    for (int j = 0; j < 10; ++j)
        if (uv[j] >= 0) {
            int pos = atomicAdd(&hist[uv[j] >> 6], 1);
            sbu[pos] = (ushort)uv[j];
        }
    __syncthreads();
    for (int i = t; i < len; i += 256) usort[e0 + i] = sbu[i];
    for (int i = t; i < NB; i += 256) hist[i] = 0;
    __syncthreads();

    // ======== pass V
#pragma unroll
    for (int j = 0; j < 10; ++j)
        if (vv[j] >= 0) atomicAdd(&hist[vv[j] >> 6], 1);
    __syncthreads();
    {
        int h0 = (i0 + 0 < NB) ? hist[i0 + 0] : 0;
        int h1 = (i0 + 1 < NB) ? hist[i0 + 1] : 0;
        int h2 = (i0 + 2 < NB) ? hist[i0 + 2] : 0;
        int h3 = (i0 + 3 < NB) ? hist[i0 + 3] : 0;
        int p1 = h0, p2 = h0 + h1, p3 = p2 + h2, p4 = p3 + h3;
        int inc = p4;
        for (int o = 1; o < 64; o <<= 1) {
            int x = __shfl_up(inc, o, 64);
            if (l >= o) inc += x;
        }
        if (l == 63) wsum[w] = inc;
        __syncthreads();
        int base = 0;
#pragma unroll
        for (int j = 0; j < 4; ++j) if (j < w) base += wsum[j];
        int total = wsum[0] + wsum[1] + wsum[2] + wsum[3];
        int excl = base + inc - p4;
        int* lpv = lpart_v + s * (NB + 1);
        if (i0 + 0 < NB) { lpv[i0 + 0] = excl;      hist[i0 + 0] = excl; }
        if (i0 + 1 < NB) { lpv[i0 + 1] = excl + p1; hist[i0 + 1] = excl + p1; }
        if (i0 + 2 < NB) { lpv[i0 + 2] = excl + p2; hist[i0 + 2] = excl + p2; }
        if (i0 + 3 < NB) { lpv[i0 + 3] = excl + p3; hist[i0 + 3] = excl + p3; }
        if (t == 255) lpv[NB] = total;
    }
    __syncthreads();
#pragma unroll
    for (int j = 0; j < 10; ++j)
        if (vv[j] >= 0) {
            int pos = atomicAdd(&hist[vv[j] >> 6], 1);
            sbv[pos] = uv[j] | ((vv[j] & 63) << 16);
        }
    __syncthreads();
    for (int i = t; i < len; i += 256) ebuf[e0 + i] = sbv[i];
}

// two-stage GEMM0: Ph = (H @ E0) @ U0 (no bias; biases folded into c/d).
__device__ __forceinline__ void gemm0_body(char* smem, int blk,
                                           const float* __restrict__ H,
                                           const float* __restrict__ E0,
                                           const float* __restrict__ U0,
                                           __half* __restrict__ Ph) {
    float (*As)[68] = (float(*)[68])smem;
    float (*Bs)[64] = (float(*)[64])(smem + 17408);
    int t = threadIdx.x;
    int row0 = blk * 64;
#pragma unroll
    for (int i = 0; i < 4; ++i) {
        int idx = t + i * 256;
        int r = idx >> 4, c = (idx & 15) << 2;
        float4 val = make_float4(0.f, 0.f, 0.f, 0.f);
        if (row0 + r < NN) val = *(const float4*)&H[(size_t)(row0 + r) * DIM + c];
        *(float4*)&As[r][c] = val;
        *(float4*)&Bs[r][c] = *(const float4*)&E0[r * DIM + c];
    }
    __syncthreads();
    int r0 = (t >> 4) * 4;
    int c0 = (t & 15) * 4;
    float acc[4][4] = {};
#pragma unroll
    for (int k = 0; k < 64; k += 4) {
        float4 b0 = *(float4*)&Bs[k + 0][c0];
        float4 b1 = *(float4*)&Bs[k + 1][c0];
        float4 b2 = *(float4*)&Bs[k + 2][c0];
        float4 b3 = *(float4*)&Bs[k + 3][c0];
#pragma unroll
        for (int i = 0; i < 4; ++i) {
            float4 av = *(float4*)&As[r0 + i][k];
            acc[i][0] = fmaf(av.x, b0.x, fmaf(av.y, b1.x, fmaf(av.z, b2.x, fmaf(av.w, b3.x, acc[i][0]))));
            acc[i][1] = fmaf(av.x, b0.y, fmaf(av.y, b1.y, fmaf(av.z, b2.y, fmaf(av.w, b3.y, acc[i][1]))));
            acc[i][2] = fmaf(av.x, b0.z, fmaf(av.y, b1.z, fmaf(av.z, b2.z, fmaf(av.w, b3.z, acc[i][2]))));
            acc[i][3] = fmaf(av.x, b0.w, fmaf(av.y, b1.w, fmaf(av.z, b2.w, fmaf(av.w, b3.w, acc[i][3]))));
        }
    }
    __syncthreads();
#pragma unroll
    for (int i = 0; i < 4; ++i)
        *(float4*)&As[r0 + i][c0] = make_float4(acc[i][0], acc[i][1], acc[i][2], acc[i][3]);
#pragma unroll
    for (int i = 0; i < 4; ++i) {
        int idx = t + i * 256;
        int r = idx >> 4, c = (idx & 15) << 2;
        *(float4*)&Bs[r][c] = *(const float4*)&U0[r * DIM + c];
    }
    __syncthreads();
    float acc2[4][4] = {};
#pragma unroll
    for (int k = 0; k < 64; k += 4) {
        float4 b0 = *(float4*)&Bs[k + 0][c0];
        float4 b1 = *(float4*)&Bs[k + 1][c0];
        float4 b2 = *(float4*)&Bs[k + 2][c0];
        float4 b3 = *(float4*)&Bs[k + 3][c0];
#pragma unroll
        for (int i = 0; i < 4; ++i) {
            float4 av = *(float4*)&As[r0 + i][k];
            acc2[i][0] = fmaf(av.x, b0.x, fmaf(av.y, b1.x, fmaf(av.z, b2.x, fmaf(av.w, b3.x, acc2[i][0]))));
            acc2[i][1] = fmaf(av.x, b0.y, fmaf(av.y, b1.y, fmaf(av.z, b2.y, fmaf(av.w, b3.y, acc2[i][1]))));
            acc2[i][2] = fmaf(av.x, b0.z, fmaf(av.y, b1.z, fmaf(av.z, b2.z, fmaf(av.w, b3.z, acc2[i][2]))));
            acc2[i][3] = fmaf(av.x, b0.w, fmaf(av.y, b1.w, fmaf(av.z, b2.w, fmaf(av.w, b3.w, acc2[i][3]))));
        }
    }
#pragma unroll
    for (int i = 0; i < 4; ++i) {
        int r = row0 + r0 + i;
        if (r < NN) {
            __half2 p0 = __floats2half2_rn(acc2[i][0], acc2[i][1]);
            __half2 p1 = __floats2half2_rn(acc2[i][2], acc2[i][3]);
            uint2 pk;
            pk.x = *(unsigned int*)&p0;
            pk.y = *(unsigned int*)&p1;
            *(uint2*)&Ph[(size_t)r * DIM + c0] = pk;
        }
    }
}

// fused front: [0,256)+[512,768) sort; [256,512)+[768,1294) GEMM0; [1294,1297) fold.
__global__ __launch_bounds__(256, 2) void k_front(const int* __restrict__ ei,
                                                  ushort* __restrict__ usort,
                                                  int* __restrict__ ebuf,
                                                  int* __restrict__ lpart_u,
                                                  int* __restrict__ lpart_v,
                                                  const float* __restrict__ H,
                                                  const float* __restrict__ E0, const float* __restrict__ e0,
                                                  const float* __restrict__ U0, const float* __restrict__ ub0,
                                                  const float* __restrict__ E1, const float* __restrict__ e1,
                                                  const float* __restrict__ U1, const float* __restrict__ ub1,
                                                  const float* __restrict__ E2, const float* __restrict__ e2,
                                                  const float* __restrict__ U2, const float* __restrict__ ub2,
                                                  __half* __restrict__ Ph,
                                                  float* __restrict__ Wp,
                                                  float* __restrict__ cvec,
                                                  float* __restrict__ dvec) {
    extern __shared__ char smem[];
    int b = blockIdx.x;
    if (b < 256)
        lsort_body(smem, ei, usort, ebuf, lpart_u, lpart_v, b);
    else if (b < 512)
        gemm0_body(smem, b - 256, H, E0, U0, Ph);
    else if (b < 768)
        lsort_body(smem, ei, usort, ebuf, lpart_u, lpart_v, b - 256);
    else if (b < 512 + GB)
        gemm0_body(smem, b - 512, H, E0, U0, Ph);
    else {
        int i = b - (512 + GB);
        const float* E  = (i == 0) ? E0  : (i == 1) ? E1  : E2;
        const float* e  = (i == 0) ? e0  : (i == 1) ? e1  : e2;
        const float* U  = (i == 0) ? U0  : (i == 1) ? U1  : U2;
        const float* ub = (i == 0) ? ub0 : (i == 1) ? ub1 : ub2;
        fold_body(smem, i, E, e, U, ub, Wp, cvec, dvec);
    }
}

// ---------------- merged mid+vsort: blocks [0,NB) u-count -> dis;
// [NB,2NB) per-bucket counting sort. Block 0 zeroes colsum.
__global__ __launch_bounds__(256) void k_prep(const ushort* __restrict__ usort,
                                              const int* __restrict__ lpart_u,
                                              const int* __restrict__ ebuf,
                                              const int* __restrict__ lpart_v,
                                              float* __restrict__ dis,
                                              ushort* __restrict__ edges,
                                              int* __restrict__ row_ptr,
                                              float* __restrict__ colsum) {
    __shared__ int cache[VCAP];
    __shared__ int cnt[64];
    __shared__ int cur[64];
    __shared__ int wsum4[4];
    __shared__ int rsum4[4];
    __shared__ int sh[64];
    int bid = blockIdx.x;
    int t = threadIdx.x, w = t >> 6, l = t & 63;
    if (bid < NB) {
        int b = bid;
        if (b == 0 && t < 64) colsum[t] = 0.f;
        if (t < 64) sh[t] = 0;
        __syncthreads();
        for (int s = t; s < SLICES; s += 256) {
            const int* row = lpart_u + s * (NB + 1);
            int st = row[b], en = row[b + 1];
            for (int i = st; i < en; ++i)
                atomicAdd(&sh[usort[s * ES + i] & 63], 1);
        }
        __syncthreads();
        int n = (b << 6) + t;
        if (t < 64 && n < NN) dis[n] = rsqrtf((float)sh[t] + 1.0f);
        return;
    }
    int b = bid - NB;
    int s0 = t * 2, s1 = t * 2 + 1;
    const int* r0p = lpart_v + s0 * (NB + 1);
    const int* r1p = lpart_v + s1 * (NB + 1);
    int a0 = r0p[b], a1 = r0p[b + 1];
    int c0 = r1p[b], c1 = r1p[b + 1];
    int len0 = a1 - a0, len1 = c1 - c0;
    int tl = len0 + len1;
    int ts = a0 + c0;
    int inc = tl;
    for (int o = 1; o < 64; o <<= 1) {
        int x = __shfl_up(inc, o, 64);
        if (l >= o) inc += x;
    }
    int tss = ts;
    for (int off = 32; off; off >>= 1) tss += __shfl_down(tss, off, 64);
    if (l == 63) wsum4[w] = inc;
    if (l == 0) rsum4[w] = tss;
    if (t < 64) cnt[t] = 0;
    __syncthreads();
    int base = 0;
#pragma unroll
    for (int j = 0; j < 4; ++j) if (j < w) base += wsum4[j];
    int n = wsum4[0] + wsum4[1] + wsum4[2] + wsum4[3];
    int rbase = rsum4[0] + rsum4[1] + rsum4[2] + rsum4[3];
    int pos = base + inc - tl;
    if (n <= VCAP) {
        for (int i = 0; i < len0; ++i) cache[pos + i] = ebuf[s0 * ES + a0 + i];
        int pos1 = pos + len0;
        for (int i = 0; i < len1; ++i) cache[pos1 + i] = ebuf[s1 * ES + c0 + i];
        __syncthreads();
        for (int i = t; i < n; i += 256)
            atomicAdd(&cnt[(cache[i] >> 16) & 63], 1);
        __syncthreads();
        if (w == 0) {
            int c = cnt[l];
            int inc2 = c;
            for (int o = 1; o < 64; o <<= 1) {
                int x = __shfl_up(inc2, o, 64);
                if (l >= o) inc2 += x;
            }
            int excl = inc2 - c;
            cur[l] = rbase + excl;
            row_ptr[(b << 6) + l] = rbase + excl;
        }
        __syncthreads();
        for (int i = t; i < n; i += 256) {
            int rec = cache[i];
            int p2 = atomicAdd(&cur[(rec >> 16) & 63], 1);
            edges[p2] = (ushort)(rec & 0xFFFF);
        }
    } else {
        for (int s = t; s < SLICES; s += 256) {
            const int* row = lpart_v + s * (NB + 1);
            int st = row[b], en = row[b + 1];
            for (int i = st; i < en; ++i)
                atomicAdd(&cnt[(ebuf[s * ES + i] >> 16) & 63], 1);
        }
        __syncthreads();
        if (w == 0) {
            int c = cnt[l];
            int inc2 = c;
            for (int o = 1; o < 64; o <<= 1) {
                int x = __shfl_up(inc2, o, 64);
                if (l >= o) inc2 += x;
            }
            int excl = inc2 - c;
            cur[l] = rbase + excl;
            row_ptr[(b << 6) + l] = rbase + excl;
        }
        __syncthreads();
        for (int s = t; s < SLICES; s += 256) {
            const int* row = lpart_v + s * (NB + 1);
            int st = row[b], en = row[b + 1];
            for (int i = st; i < en; ++i) {
                int rec = ebuf[s * ES + i];
                int p2 = atomicAdd(&cur[(rec >> 16) & 63], 1);
                edges[p2] = (ushort)(rec & 0xFFFF);
            }
        }
    }
}

// ---------------- per-node agg (one node per wave call). Returns out[0..7]
// (valid on g==0 lanes). Chain shortened to 2 round trips: edges->LDS, then
// {dis, P} gathers issued together (dis masked to 0 for padding lanes).
template<bool FIRST>
__device__ __forceinline__ void agg_node(const uint4* __restrict__ Pq4,
                                         const float* __restrict__ dis,
                                         const int* __restrict__ row_ptr,
                                         const ushort* __restrict__ edges,
                                         const float* __restrict__ cvec,
                                         const float* __restrict__ dvec,
                                         float* __restrict__ sarr,
                                         ushort* se,                 // this wave's [64] stage
                                         int node, int l, int g, int p,
                                         float out[8]) {
    int start = row_ptr[node];
    int num = row_ptr[node + 1] - start;
    uint4 pv = Pq4[(node << 3) + p];     // self row: independent, issue early
    float4 a0 = {0.f, 0.f, 0.f, 0.f};
    float4 a1 = {0.f, 0.f, 0.f, 0.f};
    float sw = 0.f;
    for (int base = 0; base < num; base += 64) {
        int lim = min(64, num - base);
        se[l] = (l < lim) ? edges[start + base + l] : 0;
        __builtin_amdgcn_wave_barrier();
        int octs = (lim + 7) >> 3;
        int rr[8]; float ww[8]; uint4 hh[8];
#pragma unroll
        for (int q = 0; q < 8; ++q)
            if (q < octs) rr[q] = se[8 * q + g];
#pragma unroll
        for (int q = 0; q < 8; ++q)
            if (q < octs) hh[q] = Pq4[(rr[q] << 3) + p];
#pragma unroll
        for (int q = 0; q < 8; ++q)
            if (q < octs) ww[q] = (8 * q + g < lim) ? dis[rr[q]] : 0.f;
#pragma unroll
        for (int q = 0; q < 8; ++q)
            if (q < octs) {
                float wt = ww[q];
                if (FIRST) sw += wt;
                float2 f0 = __half22float2(*(const __half2*)&hh[q].x);
                float2 f1 = __half22float2(*(const __half2*)&hh[q].y);
                float2 f2 = __half22float2(*(const __half2*)&hh[q].z);
                float2 f3 = __half22float2(*(const __half2*)&hh[q].w);
                a0.x = fmaf(wt, f0.x, a0.x);
                a0.y = fmaf(wt, f0.y, a0.y);
                a0.z = fmaf(wt, f1.x, a0.z);
                a0.w = fmaf(wt, f1.y, a0.w);
                a1.x = fmaf(wt, f2.x, a1.x);
                a1.y = fmaf(wt, f2.y, a1.y);
                a1.z = fmaf(wt, f3.x, a1.z);
                a1.w = fmaf(wt, f3.y, a1.w);
            }
        __builtin_amdgcn_wave_barrier();
    }
#pragma unroll
    for (int m = 8; m < 64; m <<= 1) {      // sums across g; p preserved
        a0.x += __shfl_xor(a0.x, m, 64);
        a0.y += __shfl_xor(a0.y, m, 64);
        a0.z += __shfl_xor(a0.z, m, 64);
        a0.w += __shfl_xor(a0.w, m, 64);
        a1.x += __shfl_xor(a1.x, m, 64);
        a1.y += __shfl_xor(a1.y, m, 64);
        a1.z += __shfl_xor(a1.z, m, 64);
        a1.w += __shfl_xor(a1.w, m, 64);
        if (FIRST) sw += __shfl_xor(sw, m, 64);
    }
    if (g == 0) {
        float dv = dis[node];
        float sv;
        if (FIRST) {
            sv = dv * sw;
            if (p == 0) sarr[node] = sv;
        } else {
            sv = sarr[node];
        }
        float2 s0 = __half22float2(*(const __half2*)&pv.x);
        float2 s1 = __half22float2(*(const __half2*)&pv.y);
        float2 s2 = __half22float2(*(const __half2*)&pv.z);
        float2 s3 = __half22float2(*(const __half2*)&pv.w);
        float4 cA = *(const float4*)&cvec[p << 3];
        float4 cB = *(const float4*)&cvec[(p << 3) + 4];
        float4 dA = *(const float4*)&dvec[p << 3];
        float4 dB = *(const float4*)&dvec[(p << 3) + 4];
        out[0] = fmaxf(fmaf(dv, a0.x, s0.x) + fmaf(sv, cA.x, dA.x), 0.f);
        out[1] = fmaxf(fmaf(dv, a0.y, s0.y) + fmaf(sv, cA.y, dA.y), 0.f);
        out[2] = fmaxf(fmaf(dv, a0.z, s1.x) + fmaf(sv, cA.z, dA.z), 0.f);
        out[3] = fmaxf(fmaf(dv, a0.w, s1.y) + fmaf(sv, cA.w, dA.w), 0.f);
        out[4] = fmaxf(fmaf(dv, a1.x, s2.x) + fmaf(sv, cB.x, dB.x), 0.f);
        out[5] = fmaxf(fmaf(dv, a1.y, s2.y) + fmaf(sv, cB.y, dB.y), 0.f);
        out[6] = fmaxf(fmaf(dv, a1.z, s3.x) + fmaf(sv, cB.z, dB.z), 0.f);
        out[7] = fmaxf(fmaf(dv, a1.w, s3.y) + fmaf(sv, cB.w, dB.w), 0.f);
    }
}

// ---------------- fused agg+GEMM: 16 nodes/block (1 node/wave x 4 rounds).
// Per-WAVE 4x64 GEMM: single __syncthreads after Bs preload, then waves run
// fully independently (no straggler coupling at a post-agg barrier).
template<bool FIRST>
__global__ __launch_bounds__(256) void k_agggemm(const uint4* __restrict__ Pq4,
                                                 const float* __restrict__ dis,
                                                 const int* __restrict__ row_ptr,
                                                 const ushort* __restrict__ edges,
                                                 const float* __restrict__ cvec,
                                                 const float* __restrict__ dvec,
                                                 float* __restrict__ sarr,
                                                 const float* __restrict__ W,
                                                 __half* __restrict__ Phout) {
    __shared__ float As[16][68];
    __shared__ float Bs[64][64];
    __shared__ ushort se[4][64];
    int t = threadIdx.x, w = t >> 6, l = t & 63;
    int g = l >> 3, p = l & 7;
    int node0 = blockIdx.x << 4;
    // preload W' -> LDS; the ONLY block-wide barrier in the kernel
#pragma unroll
    for (int i = 0; i < 4; ++i) {
        int idx = t + i * 256;
        int r = idx >> 4, c = (idx & 15) << 2;
        *(float4*)&Bs[r][c] = *(const float4*)&W[r * 64 + c];
    }
    __syncthreads();
#pragma unroll 1
    for (int nn = 0; nn < 4; ++nn) {
        int node = node0 + (w << 2) + nn;
        float out[8];
        agg_node<FIRST>(Pq4, dis, row_ptr, edges, cvec, dvec, sarr,
                        se[w], node, l, g, p, out);
        if (g == 0) {
            int r = (w << 2) + nn;
            *(float4*)&As[r][p << 3] = make_float4(out[0], out[1], out[2], out[3]);
            *(float4*)&As[r][(p << 3) + 4] = make_float4(out[4], out[5], out[6], out[7]);
        }
    }
    __builtin_amdgcn_wave_barrier();
    // per-wave 4x64 GEMM on the wave's own rows
    int r = (w << 2) + (l >> 4);
    int c0 = (l & 15) << 2;
    float acc0 = 0.f, acc1 = 0.f, acc2 = 0.f, acc3 = 0.f;
#pragma unroll
    for (int k = 0; k < 64; k += 4) {
        float4 b0 = *(float4*)&Bs[k + 0][c0];
        float4 b1 = *(float4*)&Bs[k + 1][c0];
        float4 b2 = *(float4*)&Bs[k + 2][c0];
        float4 b3 = *(float4*)&Bs[k + 3][c0];
        float4 av = *(float4*)&As[r][k];
        acc0 = fmaf(av.x, b0.x, fmaf(av.y, b1.x, fmaf(av.z, b2.x, fmaf(av.w, b3.x, acc0))));
        acc1 = fmaf(av.x, b0.y, fmaf(av.y, b1.y, fmaf(av.z, b2.y, fmaf(av.w, b3.y, acc1))));
        acc2 = fmaf(av.x, b0.z, fmaf(av.y, b1.z, fmaf(av.z, b2.z, fmaf(av.w, b3.z, acc2))));
        acc3 = fmaf(av.x, b0.w, fmaf(av.y, b1.w, fmaf(av.z, b2.w, fmaf(av.w, b3.w, acc3))));
    }
    __half2 h0 = __floats2half2_rn(acc0, acc1);
    __half2 h1 = __floats2half2_rn(acc2, acc3);
    uint2 pk;
    pk.x = *(unsigned int*)&h0;
    pk.y = *(unsigned int*)&h1;
    *(uint2*)&Phout[(size_t)(node0 + r) * DIM + c0] = pk;
}

// ---------------- layer-3 agg + fused column-sum (no Hh round trip)
__global__ __launch_bounds__(256) void k_aggsum(const uint4* __restrict__ Pq4,
                                                const float* __restrict__ dis,
                                                const int* __restrict__ row_ptr,
                                                const ushort* __restrict__ edges,
                                                const float* __restrict__ cvec,
                                                const float* __restrict__ dvec,
                                                float* __restrict__ sarr,
                                                float* __restrict__ colsum) {
    __shared__ ushort se[4][64];
    __shared__ float scs[64];
    int t = threadIdx.x, w = t >> 6, l = t & 63;
    int g = l >> 3, p = l & 7;
    if (t < 64) scs[t] = 0.f;
    __syncthreads();
    int node0 = blockIdx.x << 4;
    float cs[8] = {};
#pragma unroll 1
    for (int nn = 0; nn < 4; ++nn) {
        int node = node0 + (w << 2) + nn;
        float out[8];
        agg_node<false>(Pq4, dis, row_ptr, edges, cvec, dvec, sarr,
                        se[w], node, l, g, p, out);
        if (g == 0) {
#pragma unroll
            for (int j = 0; j < 8; ++j) cs[j] += out[j];
        }
    }
    if (g == 0) {
#pragma unroll
        for (int j = 0; j < 8; ++j) atomicAdd(&scs[(p << 3) + j], cs[j]);
    }
    __syncthreads();
    if (t < 64) atomicAdd(&colsum[t], scs[t]);
}

// ---------------- readout
__global__ void k_out(const float* __restrict__ colsum, const float* __restrict__ out_w,
                      const float* __restrict__ out_b, float* __restrict__ out) {
    int f = threadIdx.x;
    float v = colsum[f] * (1.0f / (float)NN) * out_w[f];
    for (int off = 32; off; off >>= 1) v += __shfl_down(v, off, 64);
    if (f == 0) out[0] = v + out_b[0];
}

extern "C" void kernel_launch(void* const* d_in, const int* in_sizes, int n_in,
                              void* d_out, int out_size, void* d_ws, size_t ws_size,
                              hipStream_t stream) {
    const float* H  = (const float*)d_in[0];
    const int*   ei = (const int*)d_in[1];
    const float* enc_w[3] = { (const float*)d_in[3], (const float*)d_in[7],  (const float*)d_in[11] };
    const float* enc_b[3] = { (const float*)d_in[4], (const float*)d_in[8],  (const float*)d_in[12] };
    const float* upd_w[3] = { (const float*)d_in[5], (const float*)d_in[9],  (const float*)d_in[13] };
    const float* upd_b[3] = { (const float*)d_in[6], (const float*)d_in[10], (const float*)d_in[14] };
    const float* out_w = (const float*)d_in[15];
    const float* out_b = (const float*)d_in[16];
    float* out = (float*)d_out;

    size_t off = 0;
    auto carve = [&](size_t bytes) {
        void* p = (char*)d_ws + off;
        off = (off + bytes + 255) & ~(size_t)255;
        return p;
    };
    int*    lpart_u = (int*)carve((size_t)SLICES * (NB + 1) * 4);
    int*    lpart_v = (int*)carve((size_t)SLICES * (NB + 1) * 4);
    float*  dis     = (float*)carve((size_t)NN * 4);
    float*  sarr    = (float*)carve((size_t)NN * 4);
    ushort* usort   = (ushort*)carve((size_t)SLICES * ES * 2);
    int*    ebuf    = (int*)carve((size_t)SLICES * ES * 4);
    ushort* edges   = (ushort*)carve((size_t)NE * 2);
    int*    row_ptr = (int*)carve((size_t)(NN + 65) * 4);
    __half* PhA     = (__half*)carve((size_t)NN * DIM * 2);
    __half* PhB     = (__half*)carve((size_t)NN * DIM * 2);
    float*  Wp      = (float*)carve(3 * 64 * 64 * 4);
    float*  cvec    = (float*)carve(3 * 64 * 4);
    float*  dvec    = (float*)carve(3 * 64 * 4);
    float*  colsum  = (float*)carve(64 * 4);

    const uint4* PqA = (const uint4*)PhA;
    const uint4* PqB = (const uint4*)PhB;

    // front: 512 sorts + PhA = (H@E0)@U0 (two-stage, no fold dep) + 3 fold blocks
    k_front<<<512 + GB + 3, 256, FRONT_LDS, stream>>>(ei, usort, ebuf, lpart_u, lpart_v, H,
                                                      enc_w[0], enc_b[0], upd_w[0], upd_b[0],
                                                      enc_w[1], enc_b[1], upd_w[1], upd_b[1],
                                                      enc_w[2], enc_b[2], upd_w[2], upd_b[2],
                                                      PhA, Wp, cvec, dvec);
    k_prep<<<2 * NB, 256, 0, stream>>>(usort, lpart_u, ebuf, lpart_v,
                                       dis, edges, row_ptr, colsum);

    // layer 1 fused: agg(PhA)+epilogue -> per-wave gemm -> PhB (computes s_v)
    k_agggemm<true><<<FB, 256, 0, stream>>>(PqA, dis, row_ptr, edges,
                                            cvec + 0, dvec + 0, sarr, Wp + 4096, PhB);
    // layer 2 fused: agg(PhB) -> per-wave gemm -> PhA
    k_agggemm<false><<<FB, 256, 0, stream>>>(PqB, dis, row_ptr, edges,
                                             cvec + 64, dvec + 64, sarr, Wp + 8192, PhA);
    // layer 3: agg(PhA) + fused colsum
    k_aggsum<<<FB, 256, 0, stream>>>(PqA, dis, row_ptr, edges,
                                     cvec + 128, dvec + 128, sarr, colsum);

    k_out<<<1, 64, 0, stream>>>(colsum, out_w, out_b, out);
}

// Round 10
// 324.623 us; speedup vs baseline: 1.1150x; 1.1150x over previous
//
#include <hip/hip_runtime.h>
#include <hip/hip_fp16.h>

#define NN 50000
#define NE 1200000
#define DIM 64
#define NB 782            // node buckets of 64: ceil(50000/64)
#define SLICES 512
#define ES 2344           // ceil(NE/SLICES); 512*2344 = 1200128 >= NE
#define VCAP 2048         // vsort bucket cache cap (mean 1536, ~13 sigma)
#define GB 782            // gemm blocks: ceil(NN/64)
#define FRONT_LDS 33792   // max(lsort ~18.3KB, gemm 33.8KB, fold 32KB)
#define AGB 6250          // fused agg+gemm blocks: NN/8 (8 nodes/block, 2/wave)

// ---------------- fold body (runs inside k_front's tail blocks):
// W'_i = enc_w_i @ upd_w_i, c_i = enc_b_i @ upd_w_i, d_i = c_i + upd_b_i.
__device__ __forceinline__ void fold_body(char* smem, int i,
                                          const float* __restrict__ E,
                                          const float* __restrict__ e,
                                          const float* __restrict__ U,
                                          const float* __restrict__ ub,
                                          float* __restrict__ Wp,
                                          float* __restrict__ cvec,
                                          float* __restrict__ dvec) {
    float (*Es)[64] = (float(*)[64])smem;
    float (*Us)[64] = (float(*)[64])(smem + 16384);
    int t = threadIdx.x;
#pragma unroll
    for (int j = 0; j < 4; ++j) {
        int idx = t + j * 256;
        int r = idx >> 4, c = (idx & 15) << 2;
        *(float4*)&Es[r][c] = *(const float4*)&E[r * 64 + c];
        *(float4*)&Us[r][c] = *(const float4*)&U[r * 64 + c];
    }
    __syncthreads();
    int r0 = (t >> 4) * 4;
    int c0 = (t & 15) * 4;
    float acc[4][4] = {};
#pragma unroll
    for (int k = 0; k < 64; k += 4) {
        float4 b0 = *(float4*)&Us[k + 0][c0];
        float4 b1 = *(float4*)&Us[k + 1][c0];
        float4 b2 = *(float4*)&Us[k + 2][c0];
        float4 b3 = *(float4*)&Us[k + 3][c0];
#pragma unroll
        for (int q = 0; q < 4; ++q) {
            float4 av = *(float4*)&Es[r0 + q][k];
            acc[q][0] = fmaf(av.x, b0.x, fmaf(av.y, b1.x, fmaf(av.z, b2.x, fmaf(av.w, b3.x, acc[q][0]))));
            acc[q][1] = fmaf(av.x, b0.y, fmaf(av.y, b1.y, fmaf(av.z, b2.y, fmaf(av.w, b3.y, acc[q][1]))));
            acc[q][2] = fmaf(av.x, b0.z, fmaf(av.y, b1.z, fmaf(av.z, b2.z, fmaf(av.w, b3.z, acc[q][2]))));
            acc[q][3] = fmaf(av.x, b0.w, fmaf(av.y, b1.w, fmaf(av.z, b2.w, fmaf(av.w, b3.w, acc[q][3]))));
        }
    }
    float* W = Wp + i * 4096;
#pragma unroll
    for (int q = 0; q < 4; ++q)
        *(float4*)&W[(r0 + q) * 64 + c0] = make_float4(acc[q][0], acc[q][1], acc[q][2], acc[q][3]);
    if (t < 64) {
        float sc = 0.f;
        for (int k = 0; k < 64; ++k) sc = fmaf(e[k], Us[k][t], sc);
        cvec[i * 64 + t] = sc;
        dvec[i * 64 + t] = sc + ub[t];
    }
}

// ================= fused front kernel bodies =================

// slice bucket-sort body, two passes (U for degrees, V for CSR build).
__device__ __forceinline__ void lsort_body(char* smem, const int* __restrict__ ei,
                                           ushort* __restrict__ usort,
                                           int* __restrict__ ebuf,
                                           int* __restrict__ lpart_u,
                                           int* __restrict__ lpart_v,
                                           int s) {
    int* hist = (int*)smem;                       // (NB+1)*4 -> pad 3136
    int* wsum = (int*)(smem + 3136);              // 4 ints
    ushort* sbu = (ushort*)(smem + 4160);         // ES*2 = 4688
    int* sbv = (int*)(smem + 8848);               // ES*4 = 9376 -> end 18224
    int t = threadIdx.x;
    int w = t >> 6, l = t & 63;
    int e0 = s * ES, e1 = min(e0 + ES, NE), len = e1 - e0;
    int i0 = t * 4;

    int uv[10], vv[10];
#pragma unroll
    for (int j = 0; j < 10; ++j) {
        int e = e0 + t + j * 256;
        uv[j] = (e < e1) ? ei[e] : -1;
        vv[j] = (e < e1) ? ei[NE + e] : -1;
    }

    // ======== pass U
    for (int i = t; i < NB; i += 256) hist[i] = 0;
    __syncthreads();
#pragma unroll
    for (int j = 0; j < 10; ++j)
        if (uv[j] >= 0) atomicAdd(&hist[uv[j] >> 6], 1);
    __syncthreads();
    {
        int h0 = (i0 + 0 < NB) ? hist[i0 + 0] : 0;
        int h1 = (i0 + 1 < NB) ? hist[i0 + 1] : 0;
        int h2 = (i0 + 2 < NB) ? hist[i0 + 2] : 0;
        int h3 = (i0 + 3 < NB) ? hist[i0 + 3] : 0;
        int p1 = h0, p2 = h0 + h1, p3 = p2 + h2, p4 = p3 + h3;
        int inc = p4;
        for (int o = 1; o < 64; o <<= 1) {
            int x = __shfl_up(inc, o, 64);
            if (l >= o) inc += x;
        }
        if (l == 63) wsum[w] = inc;
        __syncthreads();
        int base = 0;
#pragma unroll
        for (int j = 0; j < 4; ++j) if (j < w) base += wsum[j];
        int total = wsum[0] + wsum[1] + wsum[2] + wsum[3];
        int excl = base + inc - p4;
        int* lpu = lpart_u + s * (NB + 1);
        if (i0 + 0 < NB) { lpu[i0 + 0] = excl;      hist[i0 + 0] = excl; }
        if (i0 + 1 < NB) { lpu[i0 + 1] = excl + p1; hist[i0 + 1] = excl + p1; }
        if (i0 + 2 < NB) { lpu[i0 + 2] = excl + p2; hist[i0 + 2] = excl + p2; }
        if (i0 + 3 < NB) { lpu[i0 + 3] = excl + p3; hist[i0 + 3] = excl + p3; }
        if (t == 255) lpu[NB] = total;
    }
    __syncthreads();
#pragma unroll
    for (int j = 0; j < 10; ++j)
        if (uv[j] >= 0) {
            int pos = atomicAdd(&hist[uv[j] >> 6], 1);
            sbu[pos] = (ushort)uv[j];
        }
    __syncthreads();
    for (int i = t; i < len; i += 256) usort[e0 + i] = sbu[i];
    for (int i = t; i < NB; i += 256) hist[i] = 0;
    __syncthreads();

    // ======== pass V
#pragma unroll
    for (int j = 0; j < 10; ++j)
        if (vv[j] >= 0) atomicAdd(&hist[vv[j] >> 6], 1);
    __syncthreads();
    {
        int h0 = (i0 + 0 < NB) ? hist[i0 + 0] : 0;
        int h1 = (i0 + 1 < NB) ? hist[i0 + 1] : 0;
        int h2 = (i0 + 2 < NB) ? hist[i0 + 2] : 0;
        int h3 = (i0 + 3 < NB) ? hist[i0 + 3] : 0;
        int p1 = h0, p2 = h0 + h1, p3 = p2 + h2, p4 = p3 + h3;
        int inc = p4;
        for (int o = 1; o < 64; o <<= 1) {
            int x = __shfl_up(inc, o, 64);
            if (l >= o) inc += x;
        }
        if (l == 63) wsum[w] = inc;
        __syncthreads();
        int base = 0;
#pragma unroll
        for (int j = 0; j < 4; ++j) if (j < w) base += wsum[j];
        int total = wsum[0] + wsum[1] + wsum[2] + wsum[3];
        int excl = base + inc - p4;
        int* lpv = lpart_v + s * (NB + 1);
        if (i0 + 0 < NB) { lpv[i0 + 0] = excl;      hist[i0 + 0] = excl; }
        if (i0 + 1 < NB) { lpv[i0 + 1] = excl + p1; hist[i0 + 1] = excl + p1; }
        if (i0 + 2 < NB) { lpv[i0 + 2] = excl + p2; hist[i0 + 2] = excl + p2; }
        if (i0 + 3 < NB) { lpv[i0 + 3] = excl + p3; hist[i0 + 3] = excl + p3; }
        if (t == 255) lpv[NB] = total;
    }
    __syncthreads();
#pragma unroll
    for (int j = 0; j < 10; ++j)
        if (vv[j] >= 0) {
            int pos = atomicAdd(&hist[vv[j] >> 6], 1);
            sbv[pos] = uv[j] | ((vv[j] & 63) << 16);
        }
    __syncthreads();
    for (int i = t; i < len; i += 256) ebuf[e0 + i] = sbv[i];
}

// two-stage GEMM0: Ph = (H @ E0) @ U0 (no bias; biases folded into c/d).
__device__ __forceinline__ void gemm0_body(char* smem, int blk,
                                           const float* __restrict__ H,
                                           const float* __restrict__ E0,
                                           const float* __restrict__ U0,
                                           __half* __restrict__ Ph) {
    float (*As)[68] = (float(*)[68])smem;
    float (*Bs)[64] = (float(*)[64])(smem + 17408);
    int t = threadIdx.x;
    int row0 = blk * 64;
#pragma unroll
    for (int i = 0; i < 4; ++i) {
        int idx = t + i * 256;
        int r = idx >> 4, c = (idx & 15) << 2;
        float4 val = make_float4(0.f, 0.f, 0.f, 0.f);
        if (row0 + r < NN) val = *(const float4*)&H[(size_t)(row0 + r) * DIM + c];
        *(float4*)&As[r][c] = val;
        *(float4*)&Bs[r][c] = *(const float4*)&E0[r * DIM + c];
    }
    __syncthreads();
    int r0 = (t >> 4) * 4;
    int c0 = (t & 15) * 4;
    float acc[4][4] = {};
#pragma unroll
    for (int k = 0; k < 64; k += 4) {
        float4 b0 = *(float4*)&Bs[k + 0][c0];
        float4 b1 = *(float4*)&Bs[k + 1][c0];
        float4 b2 = *(float4*)&Bs[k + 2][c0];
        float4 b3 = *(float4*)&Bs[k + 3][c0];
#pragma unroll
        for (int i = 0; i < 4; ++i) {
            float4 av = *(float4*)&As[r0 + i][k];
            acc[i][0] = fmaf(av.x, b0.x, fmaf(av.y, b1.x, fmaf(av.z, b2.x, fmaf(av.w, b3.x, acc[i][0]))));
            acc[i][1] = fmaf(av.x, b0.y, fmaf(av.y, b1.y, fmaf(av.z, b2.y, fmaf(av.w, b3.y, acc[i][1]))));
            acc[i][2] = fmaf(av.x, b0.z, fmaf(av.y, b1.z, fmaf(av.z, b2.z, fmaf(av.w, b3.z, acc[i][2]))));
            acc[i][3] = fmaf(av.x, b0.w, fmaf(av.y, b1.w, fmaf(av.z, b2.w, fmaf(av.w, b3.w, acc[i][3]))));
        }
    }
    __syncthreads();
#pragma unroll
    for (int i = 0; i < 4; ++i)
        *(float4*)&As[r0 + i][c0] = make_float4(acc[i][0], acc[i][1], acc[i][2], acc[i][3]);
#pragma unroll
    for (int i = 0; i < 4; ++i) {
        int idx = t + i * 256;
        int r = idx >> 4, c = (idx & 15) << 2;
        *(float4*)&Bs[r][c] = *(const float4*)&U0[r * DIM + c];
    }
    __syncthreads();
    float acc2[4][4] = {};
#pragma unroll
    for (int k = 0; k < 64; k += 4) {
        float4 b0 = *(float4*)&Bs[k + 0][c0];
        float4 b1 = *(float4*)&Bs[k + 1][c0];
        float4 b2 = *(float4*)&Bs[k + 2][c0];
        float4 b3 = *(float4*)&Bs[k + 3][c0];
#pragma unroll
        for (int i = 0; i < 4; ++i) {
            float4 av = *(float4*)&As[r0 + i][k];
            acc2[i][0] = fmaf(av.x, b0.x, fmaf(av.y, b1.x, fmaf(av.z, b2.x, fmaf(av.w, b3.x, acc2[i][0]))));
            acc2[i][1] = fmaf(av.x, b0.y, fmaf(av.y, b1.y, fmaf(av.z, b2.y, fmaf(av.w, b3.y, acc2[i][1]))));
            acc2[i][2] = fmaf(av.x, b0.z, fmaf(av.y, b1.z, fmaf(av.z, b2.z, fmaf(av.w, b3.z, acc2[i][2]))));
            acc2[i][3] = fmaf(av.x, b0.w, fmaf(av.y, b1.w, fmaf(av.z, b2.w, fmaf(av.w, b3.w, acc2[i][3]))));
        }
    }
#pragma unroll
    for (int i = 0; i < 4; ++i) {
        int r = row0 + r0 + i;
        if (r < NN) {
            __half2 p0 = __floats2half2_rn(acc2[i][0], acc2[i][1]);
            __half2 p1 = __floats2half2_rn(acc2[i][2], acc2[i][3]);
            uint2 pk;
            pk.x = *(unsigned int*)&p0;
            pk.y = *(unsigned int*)&p1;
            *(uint2*)&Ph[(size_t)r * DIM + c0] = pk;
        }
    }
}

// fused front: [0,256)+[512,768) sort; [256,512)+[768,1294) GEMM0; [1294,1297) fold.
__global__ __launch_bounds__(256, 2) void k_front(const int* __restrict__ ei,
                                                  ushort* __restrict__ usort,
                                                  int* __restrict__ ebuf,
                                                  int* __restrict__ lpart_u,
                                                  int* __restrict__ lpart_v,
                                                  const float* __restrict__ H,
                                                  const float* __restrict__ E0, const float* __restrict__ e0,
                                                  const float* __restrict__ U0, const float* __restrict__ ub0,
                                                  const float* __restrict__ E1, const float* __restrict__ e1,
                                                  const float* __restrict__ U1, const float* __restrict__ ub1,
                                                  const float* __restrict__ E2, const float* __restrict__ e2,
                                                  const float* __restrict__ U2, const float* __restrict__ ub2,
                                                  __half* __restrict__ Ph,
                                                  float* __restrict__ Wp,
                                                  float* __restrict__ cvec,
                                                  float* __restrict__ dvec) {
    extern __shared__ char smem[];
    int b = blockIdx.x;
    if (b < 256)
        lsort_body(smem, ei, usort, ebuf, lpart_u, lpart_v, b);
    else if (b < 512)
        gemm0_body(smem, b - 256, H, E0, U0, Ph);
    else if (b < 768)
        lsort_body(smem, ei, usort, ebuf, lpart_u, lpart_v, b - 256);
    else if (b < 512 + GB)
        gemm0_body(smem, b - 512, H, E0, U0, Ph);
    else {
        int i = b - (512 + GB);
        const float* E  = (i == 0) ? E0  : (i == 1) ? E1  : E2;
        const float* e  = (i == 0) ? e0  : (i == 1) ? e1  : e2;
        const float* U  = (i == 0) ? U0  : (i == 1) ? U1  : U2;
        const float* ub = (i == 0) ? ub0 : (i == 1) ? ub1 : ub2;
        fold_body(smem, i, E, e, U, ub, Wp, cvec, dvec);
    }
}

// ---------------- merged mid+vsort: blocks [0,NB) u-count -> dis;
// [NB,2NB) per-bucket counting sort. Block 0 zeroes colsum.
__global__ __launch_bounds__(256) void k_prep(const ushort* __restrict__ usort,
                                              const int* __restrict__ lpart_u,
                                              const int* __restrict__ ebuf,
                                              const int* __restrict__ lpart_v,
                                              float* __restrict__ dis,
                                              ushort* __restrict__ edges,
                                              int* __restrict__ row_ptr,
                                              float* __restrict__ colsum) {
    __shared__ int cache[VCAP];
    __shared__ int cnt[64];
    __shared__ int cur[64];
    __shared__ int wsum4[4];
    __shared__ int rsum4[4];
    __shared__ int sh[64];
    int bid = blockIdx.x;
    int t = threadIdx.x, w = t >> 6, l = t & 63;
    if (bid < NB) {
        int b = bid;
        if (b == 0 && t < 64) colsum[t] = 0.f;
        if (t < 64) sh[t] = 0;
        __syncthreads();
        for (int s = t; s < SLICES; s += 256) {
            const int* row = lpart_u + s * (NB + 1);
            int st = row[b], en = row[b + 1];
            for (int i = st; i < en; ++i)
                atomicAdd(&sh[usort[s * ES + i] & 63], 1);
        }
        __syncthreads();
        int n = (b << 6) + t;
        if (t < 64 && n < NN) dis[n] = rsqrtf((float)sh[t] + 1.0f);
        return;
    }
    int b = bid - NB;
    int s0 = t * 2, s1 = t * 2 + 1;
    const int* r0p = lpart_v + s0 * (NB + 1);
    const int* r1p = lpart_v + s1 * (NB + 1);
    int a0 = r0p[b], a1 = r0p[b + 1];
    int c0 = r1p[b], c1 = r1p[b + 1];
    int len0 = a1 - a0, len1 = c1 - c0;
    int tl = len0 + len1;
    int ts = a0 + c0;
    int inc = tl;
    for (int o = 1; o < 64; o <<= 1) {
        int x = __shfl_up(inc, o, 64);
        if (l >= o) inc += x;
    }
    int tss = ts;
    for (int off = 32; off; off >>= 1) tss += __shfl_down(tss, off, 64);
    if (l == 63) wsum4[w] = inc;
    if (l == 0) rsum4[w] = tss;
    if (t < 64) cnt[t] = 0;
    __syncthreads();
    int base = 0;
#pragma unroll
    for (int j = 0; j < 4; ++j) if (j < w) base += wsum4[j];
    int n = wsum4[0] + wsum4[1] + wsum4[2] + wsum4[3];
    int rbase = rsum4[0] + rsum4[1] + rsum4[2] + rsum4[3];
    int pos = base + inc - tl;
    if (n <= VCAP) {
        for (int i = 0; i < len0; ++i) cache[pos + i] = ebuf[s0 * ES + a0 + i];
        int pos1 = pos + len0;
        for (int i = 0; i < len1; ++i) cache[pos1 + i] = ebuf[s1 * ES + c0 + i];
        __syncthreads();
        for (int i = t; i < n; i += 256)
            atomicAdd(&cnt[(cache[i] >> 16) & 63], 1);
        __syncthreads();
        if (w == 0) {
            int c = cnt[l];
            int inc2 = c;
            for (int o = 1; o < 64; o <<= 1) {
                int x = __shfl_up(inc2, o, 64);
                if (l >= o) inc2 += x;
            }
            int excl = inc2 - c;
            cur[l] = rbase + excl;
            row_ptr[(b << 6) + l] = rbase + excl;
        }
        __syncthreads();
        for (int i = t; i < n; i += 256) {
            int rec = cache[i];
            int p2 = atomicAdd(&cur[(rec >> 16) & 63], 1);
            edges[p2] = (ushort)(rec & 0xFFFF);
        }
    } else {
        for (int s = t; s < SLICES; s += 256) {
            const int* row = lpart_v + s * (NB + 1);
            int st = row[b], en = row[b + 1];
            for (int i = st; i < en; ++i)
                atomicAdd(&cnt[(ebuf[s * ES + i] >> 16) & 63], 1);
        }
        __syncthreads();
        if (w == 0) {
            int c = cnt[l];
            int inc2 = c;
            for (int o = 1; o < 64; o <<= 1) {
                int x = __shfl_up(inc2, o, 64);
                if (l >= o) inc2 += x;
            }
            int excl = inc2 - c;
            cur[l] = rbase + excl;
            row_ptr[(b << 6) + l] = rbase + excl;
        }
        __syncthreads();
        for (int s = t; s < SLICES; s += 256) {
            const int* row = lpart_v + s * (NB + 1);
            int st = row[b], en = row[b + 1];
            for (int i = st; i < en; ++i) {
                int rec = ebuf[s * ES + i];
                int p2 = atomicAdd(&cur[(rec >> 16) & 63], 1);
                edges[p2] = (ushort)(rec & 0xFFFF);
            }
        }
    }
}

// ---------------- per-node agg (one node per wave call). Returns out[0..7]
// (valid on g==0 lanes). 2 round trips: edges->LDS, then {dis,P} gathers
// issued together (dis masked to 0 for padding lanes).
template<bool FIRST>
__device__ __forceinline__ void agg_node(const uint4* __restrict__ Pq4,
                                         const float* __restrict__ dis,
                                         const int* __restrict__ row_ptr,
                                         const ushort* __restrict__ edges,
                                         const float* __restrict__ cvec,
                                         const float* __restrict__ dvec,
                                         float* __restrict__ sarr,
                                         ushort* se,                 // this wave's [64] stage
                                         int node, int l, int g, int p,
                                         float out[8]) {
    int start = row_ptr[node];
    int num = row_ptr[node + 1] - start;
    uint4 pv = Pq4[(node << 3) + p];     // self row: independent, issue early
    float4 a0 = {0.f, 0.f, 0.f, 0.f};
    float4 a1 = {0.f, 0.f, 0.f, 0.f};
    float sw = 0.f;
    for (int base = 0; base < num; base += 64) {
        int lim = min(64, num - base);
        se[l] = (l < lim) ? edges[start + base + l] : 0;
        __builtin_amdgcn_wave_barrier();
        int octs = (lim + 7) >> 3;
        int rr[8]; float ww[8]; uint4 hh[8];
#pragma unroll
        for (int q = 0; q < 8; ++q)
            if (q < octs) rr[q] = se[8 * q + g];
#pragma unroll
        for (int q = 0; q < 8; ++q)
            if (q < octs) hh[q] = Pq4[(rr[q] << 3) + p];
#pragma unroll
        for (int q = 0; q < 8; ++q)
            if (q < octs) ww[q] = (8 * q + g < lim) ? dis[rr[q]] : 0.f;
#pragma unroll
        for (int q = 0; q < 8; ++q)
            if (q < octs) {
                float wt = ww[q];
                if (FIRST) sw += wt;
                float2 f0 = __half22float2(*(const __half2*)&hh[q].x);
                float2 f1 = __half22float2(*(const __half2*)&hh[q].y);
                float2 f2 = __half22float2(*(const __half2*)&hh[q].z);
                float2 f3 = __half22float2(*(const __half2*)&hh[q].w);
                a0.x = fmaf(wt, f0.x, a0.x);
                a0.y = fmaf(wt, f0.y, a0.y);
                a0.z = fmaf(wt, f1.x, a0.z);
                a0.w = fmaf(wt, f1.y, a0.w);
                a1.x = fmaf(wt, f2.x, a1.x);
                a1.y = fmaf(wt, f2.y, a1.y);
                a1.z = fmaf(wt, f3.x, a1.z);
                a1.w = fmaf(wt, f3.y, a1.w);
            }
        __builtin_amdgcn_wave_barrier();
    }
#pragma unroll
    for (int m = 8; m < 64; m <<= 1) {      // sums across g; p preserved
        a0.x += __shfl_xor(a0.x, m, 64);
        a0.y += __shfl_xor(a0.y, m, 64);
        a0.z += __shfl_xor(a0.z, m, 64);
        a0.w += __shfl_xor(a0.w, m, 64);
        a1.x += __shfl_xor(a1.x, m, 64);
        a1.y += __shfl_xor(a1.y, m, 64);
        a1.z += __shfl_xor(a1.z, m, 64);
        a1.w += __shfl_xor(a1.w, m, 64);
        if (FIRST) sw += __shfl_xor(sw, m, 64);
    }
    if (g == 0) {
        float dv = dis[node];
        float sv;
        if (FIRST) {
            sv = dv * sw;
            if (p == 0) sarr[node] = sv;
        } else {
            sv = sarr[node];
        }
        float2 s0 = __half22float2(*(const __half2*)&pv.x);
        float2 s1 = __half22float2(*(const __half2*)&pv.y);
        float2 s2 = __half22float2(*(const __half2*)&pv.z);
        float2 s3 = __half22float2(*(const __half2*)&pv.w);
        float4 cA = *(const float4*)&cvec[p << 3];
        float4 cB = *(const float4*)&cvec[(p << 3) + 4];
        float4 dA = *(const float4*)&dvec[p << 3];
        float4 dB = *(const float4*)&dvec[(p << 3) + 4];
        out[0] = fmaxf(fmaf(dv, a0.x, s0.x) + fmaf(sv, cA.x, dA.x), 0.f);
        out[1] = fmaxf(fmaf(dv, a0.y, s0.y) + fmaf(sv, cA.y, dA.y), 0.f);
        out[2] = fmaxf(fmaf(dv, a0.z, s1.x) + fmaf(sv, cA.z, dA.z), 0.f);
        out[3] = fmaxf(fmaf(dv, a0.w, s1.y) + fmaf(sv, cA.w, dA.w), 0.f);
        out[4] = fmaxf(fmaf(dv, a1.x, s2.x) + fmaf(sv, cB.x, dB.x), 0.f);
        out[5] = fmaxf(fmaf(dv, a1.y, s2.y) + fmaf(sv, cB.y, dB.y), 0.f);
        out[6] = fmaxf(fmaf(dv, a1.z, s3.x) + fmaf(sv, cB.z, dB.z), 0.f);
        out[7] = fmaxf(fmaf(dv, a1.w, s3.y) + fmaf(sv, cB.w, dB.w), 0.f);
    }
}

// ---------------- fused agg+GEMM: 8 nodes/block (2 nodes/wave, 6250 blocks).
// R9 lesson applied to itself: halve per-wave serialization, double TLP.
// Per-wave 2-row x 64-col GEMM (lane -> row w*2+(l>>5), 2 cols via float2);
// single __syncthreads after Bs preload; waves never recouple.
template<bool FIRST>
__global__ __launch_bounds__(256) void k_agggemm(const uint4* __restrict__ Pq4,
                                                 const float* __restrict__ dis,
                                                 const int* __restrict__ row_ptr,
                                                 const ushort* __restrict__ edges,
                                                 const float* __restrict__ cvec,
                                                 const float* __restrict__ dvec,
                                                 float* __restrict__ sarr,
                                                 const float* __restrict__ W,
                                                 __half* __restrict__ Phout) {
    __shared__ float As[8][68];
    __shared__ float Bs[64][64];
    __shared__ ushort se[4][64];
    int t = threadIdx.x, w = t >> 6, l = t & 63;
    int g = l >> 3, p = l & 7;
    int node0 = blockIdx.x << 3;
    // preload W' -> LDS; the ONLY block-wide barrier in the kernel
#pragma unroll
    for (int i = 0; i < 4; ++i) {
        int idx = t + i * 256;
        int r = idx >> 4, c = (idx & 15) << 2;
        *(float4*)&Bs[r][c] = *(const float4*)&W[r * 64 + c];
    }
    __syncthreads();
#pragma unroll 1
    for (int nn = 0; nn < 2; ++nn) {
        int node = node0 + (w << 1) + nn;
        float out[8];
        agg_node<FIRST>(Pq4, dis, row_ptr, edges, cvec, dvec, sarr,
                        se[w], node, l, g, p, out);
        if (g == 0) {
            int r = (w << 1) + nn;
            *(float4*)&As[r][p << 3] = make_float4(out[0], out[1], out[2], out[3]);
            *(float4*)&As[r][(p << 3) + 4] = make_float4(out[4], out[5], out[6], out[7]);
        }
    }
    __builtin_amdgcn_wave_barrier();
    // per-wave 2-row GEMM: lane -> row r = w*2 + (l>>5), cols c0=(l&31)*2
    int r = (w << 1) + (l >> 5);
    int c0 = (l & 31) << 1;
    float acc0 = 0.f, acc1 = 0.f;
#pragma unroll
    for (int k = 0; k < 64; k += 4) {
        float2 b0 = *(float2*)&Bs[k + 0][c0];
        float2 b1 = *(float2*)&Bs[k + 1][c0];
        float2 b2 = *(float2*)&Bs[k + 2][c0];
        float2 b3 = *(float2*)&Bs[k + 3][c0];
        float4 av = *(float4*)&As[r][k];
        acc0 = fmaf(av.x, b0.x, fmaf(av.y, b1.x, fmaf(av.z, b2.x, fmaf(av.w, b3.x, acc0))));
        acc1 = fmaf(av.x, b0.y, fmaf(av.y, b1.y, fmaf(av.z, b2.y, fmaf(av.w, b3.y, acc1))));
    }
    __half2 h0 = __floats2half2_rn(acc0, acc1);
    *(unsigned int*)&Phout[(size_t)(node0 + r) * DIM + c0] = *(unsigned int*)&h0;
}

// ---------------- layer-3 agg (standalone, 4 nodes/block = 12500 blocks;
// R9's 3125-block fused colsum was the R4 TLP mistake again: 93us)
__global__ __launch_bounds__(256) void k_agg3(const uint4* __restrict__ Pq4,
                                              const float* __restrict__ dis,
                                              const int* __restrict__ row_ptr,
                                              const ushort* __restrict__ edges,
                                              const float* __restrict__ cvec,
                                              const float* __restrict__ dvec,
                                              float* __restrict__ sarr,
                                              __half* __restrict__ Hh) {
    __shared__ ushort se[4][64];
    int t = threadIdx.x, w = t >> 6, l = t & 63;
    int g = l >> 3, p = l & 7;
    int node = (blockIdx.x << 2) + w;
    float out[8];
    agg_node<false>(Pq4, dis, row_ptr, edges, cvec, dvec, sarr,
                    se[w], node, l, g, p, out);
    if (g == 0) {
        __half2 h0 = __floats2half2_rn(out[0], out[1]);
        __half2 h1 = __floats2half2_rn(out[2], out[3]);
        __half2 h2 = __floats2half2_rn(out[4], out[5]);
        __half2 h3 = __floats2half2_rn(out[6], out[7]);
        uint4 pk;
        pk.x = *(unsigned int*)&h0;
        pk.y = *(unsigned int*)&h1;
        pk.z = *(unsigned int*)&h2;
        pk.w = *(unsigned int*)&h3;
        *(uint4*)&Hh[((size_t)node << 6) + (p << 3)] = pk;
    }
}

// ---------------- column sums of final H (fp16) for the mean readout
__global__ __launch_bounds__(256) void k_colsum(const __half* __restrict__ Hh,
                                                float* __restrict__ colsum) {
    __shared__ float scs[64];
    int t = threadIdx.x;
    if (t < 64) scs[t] = 0.f;
    __syncthreads();
    int p = t & 7;
    float a[8] = {};
    for (int r = blockIdx.x * 32 + (t >> 3); r < NN; r += 256 * 32) {
        uint4 hv = *(const uint4*)&Hh[((size_t)r << 6) + (p << 3)];
        float2 f0 = __half22float2(*(const __half2*)&hv.x);
        float2 f1 = __half22float2(*(const __half2*)&hv.y);
        float2 f2 = __half22float2(*(const __half2*)&hv.z);
        float2 f3 = __half22float2(*(const __half2*)&hv.w);
        a[0] += f0.x; a[1] += f0.y; a[2] += f1.x; a[3] += f1.y;
        a[4] += f2.x; a[5] += f2.y; a[6] += f3.x; a[7] += f3.y;
    }
#pragma unroll
    for (int j = 0; j < 8; ++j) atomicAdd(&scs[(p << 3) + j], a[j]);
    __syncthreads();
    if (t < 64) atomicAdd(&colsum[t], scs[t]);
}

// ---------------- readout
__global__ void k_out(const float* __restrict__ colsum, const float* __restrict__ out_w,
                      const float* __restrict__ out_b, float* __restrict__ out) {
    int f = threadIdx.x;
    float v = colsum[f] * (1.0f / (float)NN) * out_w[f];
    for (int off = 32; off; off >>= 1) v += __shfl_down(v, off, 64);
    if (f == 0) out[0] = v + out_b[0];
}

extern "C" void kernel_launch(void* const* d_in, const int* in_sizes, int n_in,
                              void* d_out, int out_size, void* d_ws, size_t ws_size,
                              hipStream_t stream) {
    const float* H  = (const float*)d_in[0];
    const int*   ei = (const int*)d_in[1];
    const float* enc_w[3] = { (const float*)d_in[3], (const float*)d_in[7],  (const float*)d_in[11] };
    const float* enc_b[3] = { (const float*)d_in[4], (const float*)d_in[8],  (const float*)d_in[12] };
    const float* upd_w[3] = { (const float*)d_in[5], (const float*)d_in[9],  (const float*)d_in[13] };
    const float* upd_b[3] = { (const float*)d_in[6], (const float*)d_in[10], (const float*)d_in[14] };
    const float* out_w = (const float*)d_in[15];
    const float* out_b = (const float*)d_in[16];
    float* out = (float*)d_out;

    size_t off = 0;
    auto carve = [&](size_t bytes) {
        void* p = (char*)d_ws + off;
        off = (off + bytes + 255) & ~(size_t)255;
        return p;
    };
    int*    lpart_u = (int*)carve((size_t)SLICES * (NB + 1) * 4);
    int*    lpart_v = (int*)carve((size_t)SLICES * (NB + 1) * 4);
    float*  dis     = (float*)carve((size_t)NN * 4);
    float*  sarr    = (float*)carve((size_t)NN * 4);
    ushort* usort   = (ushort*)carve((size_t)SLICES * ES * 2);
    int*    ebuf    = (int*)carve((size_t)SLICES * ES * 4);
    ushort* edges   = (ushort*)carve((size_t)NE * 2);
    int*    row_ptr = (int*)carve((size_t)(NN + 65) * 4);
    __half* PhA     = (__half*)carve((size_t)NN * DIM * 2);
    __half* PhB     = (__half*)carve((size_t)NN * DIM * 2);
    __half* Hh      = (__half*)carve((size_t)NN * DIM * 2);
    float*  Wp      = (float*)carve(3 * 64 * 64 * 4);
    float*  cvec    = (float*)carve(3 * 64 * 4);
    float*  dvec    = (float*)carve(3 * 64 * 4);
    float*  colsum  = (float*)carve(64 * 4);

    const uint4* PqA = (const uint4*)PhA;
    const uint4* PqB = (const uint4*)PhB;

    // front: 512 sorts + PhA = (H@E0)@U0 (two-stage, no fold dep) + 3 fold blocks
    k_front<<<512 + GB + 3, 256, FRONT_LDS, stream>>>(ei, usort, ebuf, lpart_u, lpart_v, H,
                                                      enc_w[0], enc_b[0], upd_w[0], upd_b[0],
                                                      enc_w[1], enc_b[1], upd_w[1], upd_b[1],
                                                      enc_w[2], enc_b[2], upd_w[2], upd_b[2],
                                                      PhA, Wp, cvec, dvec);
    k_prep<<<2 * NB, 256, 0, stream>>>(usort, lpart_u, ebuf, lpart_v,
                                       dis, edges, row_ptr, colsum);

    // layer 1 fused: agg(PhA)+epilogue -> per-wave gemm -> PhB (computes s_v)
    k_agggemm<true><<<AGB, 256, 0, stream>>>(PqA, dis, row_ptr, edges,
                                             cvec + 0, dvec + 0, sarr, Wp + 4096, PhB);
    // layer 2 fused: agg(PhB) -> per-wave gemm -> PhA
    k_agggemm<false><<<AGB, 256, 0, stream>>>(PqB, dis, row_ptr, edges,
                                              cvec + 64, dvec + 64, sarr, Wp + 8192, PhA);
    // layer 3: agg(PhA) -> Hh (12500 blocks, 1 node/wave)
    k_agg3<<<NN / 4, 256, 0, stream>>>(PqA, dis, row_ptr, edges,
                                       cvec + 128, dvec + 128, sarr, Hh);
    k_colsum<<<256, 256, 0, stream>>>(Hh, colsum);
    k_out<<<1, 64, 0, stream>>>(colsum, out_w, out_b, out);
}

// Round 11
// 314.054 us; speedup vs baseline: 1.1525x; 1.0337x over previous
//
#include <hip/hip_runtime.h>
#include <hip/hip_fp16.h>

#define NN 50000
#define NE 1200000
#define DIM 64
#define NB 782            // node buckets of 64: ceil(50000/64)
#define SLICES 512
#define ES 2344           // ceil(NE/SLICES); 512*2344 = 1200128 >= NE
#define VCAP 2048         // vsort bucket cache cap (mean 1536, ~13 sigma)
#define GB 782            // gemm blocks: ceil(NN/64)
#define FRONT_LDS 33792   // max(lsort ~18.3KB, gemm 33.8KB, fold 32KB)
#define FB 3125           // fused agg+gemm blocks: NN/16 (16 nodes/block, 4/wave)

// ---------------- fold body (runs inside k_front's tail blocks):
// W'_i = enc_w_i @ upd_w_i, c_i = enc_b_i @ upd_w_i, d_i = c_i + upd_b_i.
__device__ __forceinline__ void fold_body(char* smem, int i,
                                          const float* __restrict__ E,
                                          const float* __restrict__ e,
                                          const float* __restrict__ U,
                                          const float* __restrict__ ub,
                                          float* __restrict__ Wp,
                                          float* __restrict__ cvec,
                                          float* __restrict__ dvec) {
    float (*Es)[64] = (float(*)[64])smem;
    float (*Us)[64] = (float(*)[64])(smem + 16384);
    int t = threadIdx.x;
#pragma unroll
    for (int j = 0; j < 4; ++j) {
        int idx = t + j * 256;
        int r = idx >> 4, c = (idx & 15) << 2;
        *(float4*)&Es[r][c] = *(const float4*)&E[r * 64 + c];
        *(float4*)&Us[r][c] = *(const float4*)&U[r * 64 + c];
    }
    __syncthreads();
    int r0 = (t >> 4) * 4;
    int c0 = (t & 15) * 4;
    float acc[4][4] = {};
#pragma unroll
    for (int k = 0; k < 64; k += 4) {
        float4 b0 = *(float4*)&Us[k + 0][c0];
        float4 b1 = *(float4*)&Us[k + 1][c0];
        float4 b2 = *(float4*)&Us[k + 2][c0];
        float4 b3 = *(float4*)&Us[k + 3][c0];
#pragma unroll
        for (int q = 0; q < 4; ++q) {
            float4 av = *(float4*)&Es[r0 + q][k];
            acc[q][0] = fmaf(av.x, b0.x, fmaf(av.y, b1.x, fmaf(av.z, b2.x, fmaf(av.w, b3.x, acc[q][0]))));
            acc[q][1] = fmaf(av.x, b0.y, fmaf(av.y, b1.y, fmaf(av.z, b2.y, fmaf(av.w, b3.y, acc[q][1]))));
            acc[q][2] = fmaf(av.x, b0.z, fmaf(av.y, b1.z, fmaf(av.z, b2.z, fmaf(av.w, b3.z, acc[q][2]))));
            acc[q][3] = fmaf(av.x, b0.w, fmaf(av.y, b1.w, fmaf(av.z, b2.w, fmaf(av.w, b3.w, acc[q][3]))));
        }
    }
    float* W = Wp + i * 4096;
#pragma unroll
    for (int q = 0; q < 4; ++q)
        *(float4*)&W[(r0 + q) * 64 + c0] = make_float4(acc[q][0], acc[q][1], acc[q][2], acc[q][3]);
    if (t < 64) {
        float sc = 0.f;
        for (int k = 0; k < 64; ++k) sc = fmaf(e[k], Us[k][t], sc);
        cvec[i * 64 + t] = sc;
        dvec[i * 64 + t] = sc + ub[t];
    }
}

// ================= fused front kernel bodies =================

// slice bucket-sort body, two passes (U for degrees, V for CSR build).
__device__ __forceinline__ void lsort_body(char* smem, const int* __restrict__ ei,
                                           ushort* __restrict__ usort,
                                           int* __restrict__ ebuf,
                                           int* __restrict__ lpart_u,
                                           int* __restrict__ lpart_v,
                                           int s) {
    int* hist = (int*)smem;                       // (NB+1)*4 -> pad 3136
    int* wsum = (int*)(smem + 3136);              // 4 ints
    ushort* sbu = (ushort*)(smem + 4160);         // ES*2 = 4688
    int* sbv = (int*)(smem + 8848);               // ES*4 = 9376 -> end 18224
    int t = threadIdx.x;
    int w = t >> 6, l = t & 63;
    int e0 = s * ES, e1 = min(e0 + ES, NE), len = e1 - e0;
    int i0 = t * 4;

    int uv[10], vv[10];
#pragma unroll
    for (int j = 0; j < 10; ++j) {
        int e = e0 + t + j * 256;
        uv[j] = (e < e1) ? ei[e] : -1;
        vv[j] = (e < e1) ? ei[NE + e] : -1;
    }

    // ======== pass U
    for (int i = t; i < NB; i += 256) hist[i] = 0;
    __syncthreads();
#pragma unroll
    for (int j = 0; j < 10; ++j)
        if (uv[j] >= 0) atomicAdd(&hist[uv[j] >> 6], 1);
    __syncthreads();
    {
        int h0 = (i0 + 0 < NB) ? hist[i0 + 0] : 0;
        int h1 = (i0 + 1 < NB) ? hist[i0 + 1] : 0;
        int h2 = (i0 + 2 < NB) ? hist[i0 + 2] : 0;
        int h3 = (i0 + 3 < NB) ? hist[i0 + 3] : 0;
        int p1 = h0, p2 = h0 + h1, p3 = p2 + h2, p4 = p3 + h3;
        int inc = p4;
        for (int o = 1; o < 64; o <<= 1) {
            int x = __shfl_up(inc, o, 64);
            if (l >= o) inc += x;
        }
        if (l == 63) wsum[w] = inc;
        __syncthreads();
        int base = 0;
#pragma unroll
        for (int j = 0; j < 4; ++j) if (j < w) base += wsum[j];
        int total = wsum[0] + wsum[1] + wsum[2] + wsum[3];
        int excl = base + inc - p4;
        int* lpu = lpart_u + s * (NB + 1);
        if (i0 + 0 < NB) { lpu[i0 + 0] = excl;      hist[i0 + 0] = excl; }
        if (i0 + 1 < NB) { lpu[i0 + 1] = excl + p1; hist[i0 + 1] = excl + p1; }
        if (i0 + 2 < NB) { lpu[i0 + 2] = excl + p2; hist[i0 + 2] = excl + p2; }
        if (i0 + 3 < NB) { lpu[i0 + 3] = excl + p3; hist[i0 + 3] = excl + p3; }
        if (t == 255) lpu[NB] = total;
    }
    __syncthreads();
#pragma unroll
    for (int j = 0; j < 10; ++j)
        if (uv[j] >= 0) {
            int pos = atomicAdd(&hist[uv[j] >> 6], 1);
            sbu[pos] = (ushort)uv[j];
        }
    __syncthreads();
    for (int i = t; i < len; i += 256) usort[e0 + i] = sbu[i];
    for (int i = t; i < NB; i += 256) hist[i] = 0;
    __syncthreads();

    // ======== pass V
#pragma unroll
    for (int j = 0; j < 10; ++j)
        if (vv[j] >= 0) atomicAdd(&hist[vv[j] >> 6], 1);
    __syncthreads();
    {
        int h0 = (i0 + 0 < NB) ? hist[i0 + 0] : 0;
        int h1 = (i0 + 1 < NB) ? hist[i0 + 1] : 0;
        int h2 = (i0 + 2 < NB) ? hist[i0 + 2] : 0;
        int h3 = (i0 + 3 < NB) ? hist[i0 + 3] : 0;
        int p1 = h0, p2 = h0 + h1, p3 = p2 + h2, p4 = p3 + h3;
        int inc = p4;
        for (int o = 1; o < 64; o <<= 1) {
            int x = __shfl_up(inc, o, 64);
            if (l >= o) inc += x;
        }
        if (l == 63) wsum[w] = inc;
        __syncthreads();
        int base = 0;
#pragma unroll
        for (int j = 0; j < 4; ++j) if (j < w) base += wsum[j];
        int total = wsum[0] + wsum[1] + wsum[2] + wsum[3];
        int excl = base + inc - p4;
        int* lpv = lpart_v + s * (NB + 1);
        if (i0 + 0 < NB) { lpv[i0 + 0] = excl;      hist[i0 + 0] = excl; }
        if (i0 + 1 < NB) { lpv[i0 + 1] = excl + p1; hist[i0 + 1] = excl + p1; }
        if (i0 + 2 < NB) { lpv[i0 + 2] = excl + p2; hist[i0 + 2] = excl + p2; }
        if (i0 + 3 < NB) { lpv[i0 + 3] = excl + p3; hist[i0 + 3] = excl + p3; }
        if (t == 255) lpv[NB] = total;
    }
    __syncthreads();
#pragma unroll
    for (int j = 0; j < 10; ++j)
        if (vv[j] >= 0) {
            int pos = atomicAdd(&hist[vv[j] >> 6], 1);
            sbv[pos] = uv[j] | ((vv[j] & 63) << 16);
        }
    __syncthreads();
    for (int i = t; i < len; i += 256) ebuf[e0 + i] = sbv[i];
}

// two-stage GEMM0: Ph = (H @ E0) @ U0 (no bias; biases folded into c/d).
__device__ __forceinline__ void gemm0_body(char* smem, int blk,
                                           const float* __restrict__ H,
                                           const float* __restrict__ E0,
                                           const float* __restrict__ U0,
                                           __half* __restrict__ Ph) {
    float (*As)[68] = (float(*)[68])smem;
    float (*Bs)[64] = (float(*)[64])(smem + 17408);
    int t = threadIdx.x;
    int row0 = blk * 64;
#pragma unroll
    for (int i = 0; i < 4; ++i) {
        int idx = t + i * 256;
        int r = idx >> 4, c = (idx & 15) << 2;
        float4 val = make_float4(0.f, 0.f, 0.f, 0.f);
        if (row0 + r < NN) val = *(const float4*)&H[(size_t)(row0 + r) * DIM + c];
        *(float4*)&As[r][c] = val;
        *(float4*)&Bs[r][c] = *(const float4*)&E0[r * DIM + c];
    }
    __syncthreads();
    int r0 = (t >> 4) * 4;
    int c0 = (t & 15) * 4;
    float acc[4][4] = {};
#pragma unroll
    for (int k = 0; k < 64; k += 4) {
        float4 b0 = *(float4*)&Bs[k + 0][c0];
        float4 b1 = *(float4*)&Bs[k + 1][c0];
        float4 b2 = *(float4*)&Bs[k + 2][c0];
        float4 b3 = *(float4*)&Bs[k + 3][c0];
#pragma unroll
        for (int i = 0; i < 4; ++i) {
            float4 av = *(float4*)&As[r0 + i][k];
            acc[i][0] = fmaf(av.x, b0.x, fmaf(av.y, b1.x, fmaf(av.z, b2.x, fmaf(av.w, b3.x, acc[i][0]))));
            acc[i][1] = fmaf(av.x, b0.y, fmaf(av.y, b1.y, fmaf(av.z, b2.y, fmaf(av.w, b3.y, acc[i][1]))));
            acc[i][2] = fmaf(av.x, b0.z, fmaf(av.y, b1.z, fmaf(av.z, b2.z, fmaf(av.w, b3.z, acc[i][2]))));
            acc[i][3] = fmaf(av.x, b0.w, fmaf(av.y, b1.w, fmaf(av.z, b2.w, fmaf(av.w, b3.w, acc[i][3]))));
        }
    }
    __syncthreads();
#pragma unroll
    for (int i = 0; i < 4; ++i)
        *(float4*)&As[r0 + i][c0] = make_float4(acc[i][0], acc[i][1], acc[i][2], acc[i][3]);
#pragma unroll
    for (int i = 0; i < 4; ++i) {
        int idx = t + i * 256;
        int r = idx >> 4, c = (idx & 15) << 2;
        *(float4*)&Bs[r][c] = *(const float4*)&U0[r * DIM + c];
    }
    __syncthreads();
    float acc2[4][4] = {};
#pragma unroll
    for (int k = 0; k < 64; k += 4) {
        float4 b0 = *(float4*)&Bs[k + 0][c0];
        float4 b1 = *(float4*)&Bs[k + 1][c0];
        float4 b2 = *(float4*)&Bs[k + 2][c0];
        float4 b3 = *(float4*)&Bs[k + 3][c0];
#pragma unroll
        for (int i = 0; i < 4; ++i) {
            float4 av = *(float4*)&As[r0 + i][k];
            acc2[i][0] = fmaf(av.x, b0.x, fmaf(av.y, b1.x, fmaf(av.z, b2.x, fmaf(av.w, b3.x, acc2[i][0]))));
            acc2[i][1] = fmaf(av.x, b0.y, fmaf(av.y, b1.y, fmaf(av.z, b2.y, fmaf(av.w, b3.y, acc2[i][1]))));
            acc2[i][2] = fmaf(av.x, b0.z, fmaf(av.y, b1.z, fmaf(av.z, b2.z, fmaf(av.w, b3.z, acc2[i][2]))));
            acc2[i][3] = fmaf(av.x, b0.w, fmaf(av.y, b1.w, fmaf(av.z, b2.w, fmaf(av.w, b3.w, acc2[i][3]))));
        }
    }
#pragma unroll
    for (int i = 0; i < 4; ++i) {
        int r = row0 + r0 + i;
        if (r < NN) {
            __half2 p0 = __floats2half2_rn(acc2[i][0], acc2[i][1]);
            __half2 p1 = __floats2half2_rn(acc2[i][2], acc2[i][3]);
            uint2 pk;
            pk.x = *(unsigned int*)&p0;
            pk.y = *(unsigned int*)&p1;
            *(uint2*)&Ph[(size_t)r * DIM + c0] = pk;
        }
    }
}

// fused front: [0,256)+[512,768) sort; [256,512)+[768,1294) GEMM0; [1294,1297) fold.
__global__ __launch_bounds__(256, 2) void k_front(const int* __restrict__ ei,
                                                  ushort* __restrict__ usort,
                                                  int* __restrict__ ebuf,
                                                  int* __restrict__ lpart_u,
                                                  int* __restrict__ lpart_v,
                                                  const float* __restrict__ H,
                                                  const float* __restrict__ E0, const float* __restrict__ e0,
                                                  const float* __restrict__ U0, const float* __restrict__ ub0,
                                                  const float* __restrict__ E1, const float* __restrict__ e1,
                                                  const float* __restrict__ U1, const float* __restrict__ ub1,
                                                  const float* __restrict__ E2, const float* __restrict__ e2,
                                                  const float* __restrict__ U2, const float* __restrict__ ub2,
                                                  __half* __restrict__ Ph,
                                                  float* __restrict__ Wp,
                                                  float* __restrict__ cvec,
                                                  float* __restrict__ dvec) {
    extern __shared__ char smem[];
    int b = blockIdx.x;
    if (b < 256)
        lsort_body(smem, ei, usort, ebuf, lpart_u, lpart_v, b);
    else if (b < 512)
        gemm0_body(smem, b - 256, H, E0, U0, Ph);
    else if (b < 768)
        lsort_body(smem, ei, usort, ebuf, lpart_u, lpart_v, b - 256);
    else if (b < 512 + GB)
        gemm0_body(smem, b - 512, H, E0, U0, Ph);
    else {
        int i = b - (512 + GB);
        const float* E  = (i == 0) ? E0  : (i == 1) ? E1  : E2;
        const float* e  = (i == 0) ? e0  : (i == 1) ? e1  : e2;
        const float* U  = (i == 0) ? U0  : (i == 1) ? U1  : U2;
        const float* ub = (i == 0) ? ub0 : (i == 1) ? ub1 : ub2;
        fold_body(smem, i, E, e, U, ub, Wp, cvec, dvec);
    }
}

// ---------------- merged mid+vsort: blocks [0,NB) u-count -> dis;
// [NB,2NB) per-bucket counting sort. Block 0 zeroes colsum.
__global__ __launch_bounds__(256) void k_prep(const ushort* __restrict__ usort,
                                              const int* __restrict__ lpart_u,
                                              const int* __restrict__ ebuf,
                                              const int* __restrict__ lpart_v,
                                              float* __restrict__ dis,
                                              ushort* __restrict__ edges,
                                              int* __restrict__ row_ptr,
                                              float* __restrict__ colsum) {
    __shared__ int cache[VCAP];
    __shared__ int cnt[64];
    __shared__ int cur[64];
    __shared__ int wsum4[4];
    __shared__ int rsum4[4];
    __shared__ int sh[64];
    int bid = blockIdx.x;
    int t = threadIdx.x, w = t >> 6, l = t & 63;
    if (bid < NB) {
        int b = bid;
        if (b == 0 && t < 64) colsum[t] = 0.f;
        if (t < 64) sh[t] = 0;
        __syncthreads();
        for (int s = t; s < SLICES; s += 256) {
            const int* row = lpart_u + s * (NB + 1);
            int st = row[b], en = row[b + 1];
            for (int i = st; i < en; ++i)
                atomicAdd(&sh[usort[s * ES + i] & 63], 1);
        }
        __syncthreads();
        int n = (b << 6) + t;
        if (t < 64 && n < NN) dis[n] = rsqrtf((float)sh[t] + 1.0f);
        return;
    }
    int b = bid - NB;
    int s0 = t * 2, s1 = t * 2 + 1;
    const int* r0p = lpart_v + s0 * (NB + 1);
    const int* r1p = lpart_v + s1 * (NB + 1);
    int a0 = r0p[b], a1 = r0p[b + 1];
    int c0 = r1p[b], c1 = r1p[b + 1];
    int len0 = a1 - a0, len1 = c1 - c0;
    int tl = len0 + len1;
    int ts = a0 + c0;
    int inc = tl;
    for (int o = 1; o < 64; o <<= 1) {
        int x = __shfl_up(inc, o, 64);
        if (l >= o) inc += x;
    }
    int tss = ts;
    for (int off = 32; off; off >>= 1) tss += __shfl_down(tss, off, 64);
    if (l == 63) wsum4[w] = inc;
    if (l == 0) rsum4[w] = tss;
    if (t < 64) cnt[t] = 0;
    __syncthreads();
    int base = 0;
#pragma unroll
    for (int j = 0; j < 4; ++j) if (j < w) base += wsum4[j];
    int n = wsum4[0] + wsum4[1] + wsum4[2] + wsum4[3];
    int rbase = rsum4[0] + rsum4[1] + rsum4[2] + rsum4[3];
    int pos = base + inc - tl;
    if (n <= VCAP) {
        for (int i = 0; i < len0; ++i) cache[pos + i] = ebuf[s0 * ES + a0 + i];
        int pos1 = pos + len0;
        for (int i = 0; i < len1; ++i) cache[pos1 + i] = ebuf[s1 * ES + c0 + i];
        __syncthreads();
        for (int i = t; i < n; i += 256)
            atomicAdd(&cnt[(cache[i] >> 16) & 63], 1);
        __syncthreads();
        if (w == 0) {
            int c = cnt[l];
            int inc2 = c;
            for (int o = 1; o < 64; o <<= 1) {
                int x = __shfl_up(inc2, o, 64);
                if (l >= o) inc2 += x;
            }
            int excl = inc2 - c;
            cur[l] = rbase + excl;
            row_ptr[(b << 6) + l] = rbase + excl;
        }
        __syncthreads();
        for (int i = t; i < n; i += 256) {
            int rec = cache[i];
            int p2 = atomicAdd(&cur[(rec >> 16) & 63], 1);
            edges[p2] = (ushort)(rec & 0xFFFF);
        }
    } else {
        for (int s = t; s < SLICES; s += 256) {
            const int* row = lpart_v + s * (NB + 1);
            int st = row[b], en = row[b + 1];
            for (int i = st; i < en; ++i)
                atomicAdd(&cnt[(ebuf[s * ES + i] >> 16) & 63], 1);
        }
        __syncthreads();
        if (w == 0) {
            int c = cnt[l];
            int inc2 = c;
            for (int o = 1; o < 64; o <<= 1) {
                int x = __shfl_up(inc2, o, 64);
                if (l >= o) inc2 += x;
            }
            int excl = inc2 - c;
            cur[l] = rbase + excl;
            row_ptr[(b << 6) + l] = rbase + excl;
        }
        __syncthreads();
        for (int s = t; s < SLICES; s += 256) {
            const int* row = lpart_v + s * (NB + 1);
            int st = row[b], en = row[b + 1];
            for (int i = st; i < en; ++i) {
                int rec = ebuf[s * ES + i];
                int p2 = atomicAdd(&cur[(rec >> 16) & 63], 1);
                edges[p2] = (ushort)(rec & 0xFFFF);
            }
        }
    }
}

// ---------------- per-node agg (one node per wave call). Returns out[0..7]
// (valid on g==0 lanes). 2 round trips: edges->LDS, then {dis,P} gathers
// issued together (dis masked to 0 for padding lanes).
template<bool FIRST>
__device__ __forceinline__ void agg_node(const uint4* __restrict__ Pq4,
                                         const float* __restrict__ dis,
                                         const int* __restrict__ row_ptr,
                                         const ushort* __restrict__ edges,
                                         const float* __restrict__ cvec,
                                         const float* __restrict__ dvec,
                                         float* __restrict__ sarr,
                                         ushort* se,                 // this wave's [64] stage
                                         int node, int l, int g, int p,
                                         float out[8]) {
    int start = row_ptr[node];
    int num = row_ptr[node + 1] - start;
    uint4 pv = Pq4[(node << 3) + p];     // self row: independent, issue early
    float4 a0 = {0.f, 0.f, 0.f, 0.f};
    float4 a1 = {0.f, 0.f, 0.f, 0.f};
    float sw = 0.f;
    for (int base = 0; base < num; base += 64) {
        int lim = min(64, num - base);
        se[l] = (l < lim) ? edges[start + base + l] : 0;
        __builtin_amdgcn_wave_barrier();
        int octs = (lim + 7) >> 3;
        int rr[8]; float ww[8]; uint4 hh[8];
#pragma unroll
        for (int q = 0; q < 8; ++q)
            if (q < octs) rr[q] = se[8 * q + g];
#pragma unroll
        for (int q = 0; q < 8; ++q)
            if (q < octs) hh[q] = Pq4[(rr[q] << 3) + p];
#pragma unroll
        for (int q = 0; q < 8; ++q)
            if (q < octs) ww[q] = (8 * q + g < lim) ? dis[rr[q]] : 0.f;
#pragma unroll
        for (int q = 0; q < 8; ++q)
            if (q < octs) {
                float wt = ww[q];
                if (FIRST) sw += wt;
                float2 f0 = __half22float2(*(const __half2*)&hh[q].x);
                float2 f1 = __half22float2(*(const __half2*)&hh[q].y);
                float2 f2 = __half22float2(*(const __half2*)&hh[q].z);
                float2 f3 = __half22float2(*(const __half2*)&hh[q].w);
                a0.x = fmaf(wt, f0.x, a0.x);
                a0.y = fmaf(wt, f0.y, a0.y);
                a0.z = fmaf(wt, f1.x, a0.z);
                a0.w = fmaf(wt, f1.y, a0.w);
                a1.x = fmaf(wt, f2.x, a1.x);
                a1.y = fmaf(wt, f2.y, a1.y);
                a1.z = fmaf(wt, f3.x, a1.z);
                a1.w = fmaf(wt, f3.y, a1.w);
            }
        __builtin_amdgcn_wave_barrier();
    }
#pragma unroll
    for (int m = 8; m < 64; m <<= 1) {      // sums across g; p preserved
        a0.x += __shfl_xor(a0.x, m, 64);
        a0.y += __shfl_xor(a0.y, m, 64);
        a0.z += __shfl_xor(a0.z, m, 64);
        a0.w += __shfl_xor(a0.w, m, 64);
        a1.x += __shfl_xor(a1.x, m, 64);
        a1.y += __shfl_xor(a1.y, m, 64);
        a1.z += __shfl_xor(a1.z, m, 64);
        a1.w += __shfl_xor(a1.w, m, 64);
        if (FIRST) sw += __shfl_xor(sw, m, 64);
    }
    if (g == 0) {
        float dv = dis[node];
        float sv;
        if (FIRST) {
            sv = dv * sw;
            if (p == 0) sarr[node] = sv;
        } else {
            sv = sarr[node];
        }
        float2 s0 = __half22float2(*(const __half2*)&pv.x);
        float2 s1 = __half22float2(*(const __half2*)&pv.y);
        float2 s2 = __half22float2(*(const __half2*)&pv.z);
        float2 s3 = __half22float2(*(const __half2*)&pv.w);
        float4 cA = *(const float4*)&cvec[p << 3];
        float4 cB = *(const float4*)&cvec[(p << 3) + 4];
        float4 dA = *(const float4*)&dvec[p << 3];
        float4 dB = *(const float4*)&dvec[(p << 3) + 4];
        out[0] = fmaxf(fmaf(dv, a0.x, s0.x) + fmaf(sv, cA.x, dA.x), 0.f);
        out[1] = fmaxf(fmaf(dv, a0.y, s0.y) + fmaf(sv, cA.y, dA.y), 0.f);
        out[2] = fmaxf(fmaf(dv, a0.z, s1.x) + fmaf(sv, cA.z, dA.z), 0.f);
        out[3] = fmaxf(fmaf(dv, a0.w, s1.y) + fmaf(sv, cA.w, dA.w), 0.f);
        out[4] = fmaxf(fmaf(dv, a1.x, s2.x) + fmaf(sv, cB.x, dB.x), 0.f);
        out[5] = fmaxf(fmaf(dv, a1.y, s2.y) + fmaf(sv, cB.y, dB.y), 0.f);
        out[6] = fmaxf(fmaf(dv, a1.z, s3.x) + fmaf(sv, cB.z, dB.z), 0.f);
        out[7] = fmaxf(fmaf(dv, a1.w, s3.y) + fmaf(sv, cB.w, dB.w), 0.f);
    }
}

// ---------------- fused agg+GEMM: 16 nodes/block (4 nodes/wave, 3125 blocks).
// R10 lesson: nodes-in-flight = resident waves (serialization depth ~free);
// fewer blocks = fewer 16KB Bs preloads. R9's shape, the measured best (~51us).
// Per-wave 4-row GEMM; single __syncthreads after Bs preload.
template<bool FIRST>
__global__ __launch_bounds__(256) void k_agggemm(const uint4* __restrict__ Pq4,
                                                 const float* __restrict__ dis,
                                                 const int* __restrict__ row_ptr,
                                                 const ushort* __restrict__ edges,
                                                 const float* __restrict__ cvec,
                                                 const float* __restrict__ dvec,
                                                 float* __restrict__ sarr,
                                                 const float* __restrict__ W,
                                                 __half* __restrict__ Phout) {
    __shared__ float As[16][68];
    __shared__ float Bs[64][64];
    __shared__ ushort se[4][64];
    int t = threadIdx.x, w = t >> 6, l = t & 63;
    int g = l >> 3, p = l & 7;
    int node0 = blockIdx.x << 4;
    // preload W' -> LDS; the ONLY block-wide barrier in the kernel
#pragma unroll
    for (int i = 0; i < 4; ++i) {
        int idx = t + i * 256;
        int r = idx >> 4, c = (idx & 15) << 2;
        *(float4*)&Bs[r][c] = *(const float4*)&W[r * 64 + c];
    }
    __syncthreads();
#pragma unroll 1
    for (int nn = 0; nn < 4; ++nn) {
        int node = node0 + (w << 2) + nn;
        float out[8];
        agg_node<FIRST>(Pq4, dis, row_ptr, edges, cvec, dvec, sarr,
                        se[w], node, l, g, p, out);
        if (g == 0) {
            int r = (w << 2) + nn;
            *(float4*)&As[r][p << 3] = make_float4(out[0], out[1], out[2], out[3]);
            *(float4*)&As[r][(p << 3) + 4] = make_float4(out[4], out[5], out[6], out[7]);
        }
    }
    __builtin_amdgcn_wave_barrier();
    // per-wave 4-row GEMM: lane -> row r = w*4 + (l>>4), cols c0=(l&15)*4
    int r = (w << 2) + (l >> 4);
    int c0 = (l & 15) << 2;
    float acc0 = 0.f, acc1 = 0.f, acc2 = 0.f, acc3 = 0.f;
#pragma unroll
    for (int k = 0; k < 64; k += 4) {
        float4 b0 = *(float4*)&Bs[k + 0][c0];
        float4 b1 = *(float4*)&Bs[k + 1][c0];
        float4 b2 = *(float4*)&Bs[k + 2][c0];
        float4 b3 = *(float4*)&Bs[k + 3][c0];
        float4 av = *(float4*)&As[r][k];
        acc0 = fmaf(av.x, b0.x, fmaf(av.y, b1.x, fmaf(av.z, b2.x, fmaf(av.w, b3.x, acc0))));
        acc1 = fmaf(av.x, b0.y, fmaf(av.y, b1.y, fmaf(av.z, b2.y, fmaf(av.w, b3.y, acc1))));
        acc2 = fmaf(av.x, b0.z, fmaf(av.y, b1.z, fmaf(av.z, b2.z, fmaf(av.w, b3.z, acc2))));
        acc3 = fmaf(av.x, b0.w, fmaf(av.y, b1.w, fmaf(av.z, b2.w, fmaf(av.w, b3.w, acc3))));
    }
    __half2 h0 = __floats2half2_rn(acc0, acc1);
    __half2 h1 = __floats2half2_rn(acc2, acc3);
    uint2 pk;
    pk.x = *(unsigned int*)&h0;
    pk.y = *(unsigned int*)&h1;
    *(uint2*)&Phout[(size_t)(node0 + r) * DIM + c0] = pk;
}

// ---------------- layer-3 agg (standalone, 4 nodes/block = 12500 blocks)
__global__ __launch_bounds__(256) void k_agg3(const uint4* __restrict__ Pq4,
                                              const float* __restrict__ dis,
                                              const int* __restrict__ row_ptr,
                                              const ushort* __restrict__ edges,
                                              const float* __restrict__ cvec,
                                              const float* __restrict__ dvec,
                                              float* __restrict__ sarr,
                                              __half* __restrict__ Hh) {
    __shared__ ushort se[4][64];
    int t = threadIdx.x, w = t >> 6, l = t & 63;
    int g = l >> 3, p = l & 7;
    int node = (blockIdx.x << 2) + w;
    float out[8];
    agg_node<false>(Pq4, dis, row_ptr, edges, cvec, dvec, sarr,
                    se[w], node, l, g, p, out);
    if (g == 0) {
        __half2 h0 = __floats2half2_rn(out[0], out[1]);
        __half2 h1 = __floats2half2_rn(out[2], out[3]);
        __half2 h2 = __floats2half2_rn(out[4], out[5]);
        __half2 h3 = __floats2half2_rn(out[6], out[7]);
        uint4 pk;
        pk.x = *(unsigned int*)&h0;
        pk.y = *(unsigned int*)&h1;
        pk.z = *(unsigned int*)&h2;
        pk.w = *(unsigned int*)&h3;
        *(uint4*)&Hh[((size_t)node << 6) + (p << 3)] = pk;
    }
}

// ---------------- column sums of final H (fp16) for the mean readout
__global__ __launch_bounds__(256) void k_colsum(const __half* __restrict__ Hh,
                                                float* __restrict__ colsum) {
    __shared__ float scs[64];
    int t = threadIdx.x;
    if (t < 64) scs[t] = 0.f;
    __syncthreads();
    int p = t & 7;
    float a[8] = {};
    for (int r = blockIdx.x * 32 + (t >> 3); r < NN; r += 256 * 32) {
        uint4 hv = *(const uint4*)&Hh[((size_t)r << 6) + (p << 3)];
        float2 f0 = __half22float2(*(const __half2*)&hv.x);
        float2 f1 = __half22float2(*(const __half2*)&hv.y);
        float2 f2 = __half22float2(*(const __half2*)&hv.z);
        float2 f3 = __half22float2(*(const __half2*)&hv.w);
        a[0] += f0.x; a[1] += f0.y; a[2] += f1.x; a[3] += f1.y;
        a[4] += f2.x; a[5] += f2.y; a[6] += f3.x; a[7] += f3.y;
    }
#pragma unroll
    for (int j = 0; j < 8; ++j) atomicAdd(&scs[(p << 3) + j], a[j]);
    __syncthreads();
    if (t < 64) atomicAdd(&colsum[t], scs[t]);
}

// ---------------- readout
__global__ void k_out(const float* __restrict__ colsum, const float* __restrict__ out_w,
                      const float* __restrict__ out_b, float* __restrict__ out) {
    int f = threadIdx.x;
    float v = colsum[f] * (1.0f / (float)NN) * out_w[f];
    for (int off = 32; off; off >>= 1) v += __shfl_down(v, off, 64);
    if (f == 0) out[0] = v + out_b[0];
}

extern "C" void kernel_launch(void* const* d_in, const int* in_sizes, int n_in,
                              void* d_out, int out_size, void* d_ws, size_t ws_size,
                              hipStream_t stream) {
    const float* H  = (const float*)d_in[0];
    const int*   ei = (const int*)d_in[1];
    const float* enc_w[3] = { (const float*)d_in[3], (const float*)d_in[7],  (const float*)d_in[11] };
    const float* enc_b[3] = { (const float*)d_in[4], (const float*)d_in[8],  (const float*)d_in[12] };
    const float* upd_w[3] = { (const float*)d_in[5], (const float*)d_in[9],  (const float*)d_in[13] };
    const float* upd_b[3] = { (const float*)d_in[6], (const float*)d_in[10], (const float*)d_in[14] };
    const float* out_w = (const float*)d_in[15];
    const float* out_b = (const float*)d_in[16];
    float* out = (float*)d_out;

    size_t off = 0;
    auto carve = [&](size_t bytes) {
        void* p = (char*)d_ws + off;
        off = (off + bytes + 255) & ~(size_t)255;
        return p;
    };
    int*    lpart_u = (int*)carve((size_t)SLICES * (NB + 1) * 4);
    int*    lpart_v = (int*)carve((size_t)SLICES * (NB + 1) * 4);
    float*  dis     = (float*)carve((size_t)NN * 4);
    float*  sarr    = (float*)carve((size_t)NN * 4);
    ushort* usort   = (ushort*)carve((size_t)SLICES * ES * 2);
    int*    ebuf    = (int*)carve((size_t)SLICES * ES * 4);
    ushort* edges   = (ushort*)carve((size_t)NE * 2);
    int*    row_ptr = (int*)carve((size_t)(NN + 65) * 4);
    __half* PhA     = (__half*)carve((size_t)NN * DIM * 2);
    __half* PhB     = (__half*)carve((size_t)NN * DIM * 2);
    __half* Hh      = (__half*)carve((size_t)NN * DIM * 2);
    float*  Wp      = (float*)carve(3 * 64 * 64 * 4);
    float*  cvec    = (float*)carve(3 * 64 * 4);
    float*  dvec    = (float*)carve(3 * 64 * 4);
    float*  colsum  = (float*)carve(64 * 4);

    const uint4* PqA = (const uint4*)PhA;
    const uint4* PqB = (const uint4*)PhB;

    // front: 512 sorts + PhA = (H@E0)@U0 (two-stage, no fold dep) + 3 fold blocks
    k_front<<<512 + GB + 3, 256, FRONT_LDS, stream>>>(ei, usort, ebuf, lpart_u, lpart_v, H,
                                                      enc_w[0], enc_b[0], upd_w[0], upd_b[0],
                                                      enc_w[1], enc_b[1], upd_w[1], upd_b[1],
                                                      enc_w[2], enc_b[2], upd_w[2], upd_b[2],
                                                      PhA, Wp, cvec, dvec);
    k_prep<<<2 * NB, 256, 0, stream>>>(usort, lpart_u, ebuf, lpart_v,
                                       dis, edges, row_ptr, colsum);

    // layer 1 fused: agg(PhA)+epilogue -> per-wave gemm -> PhB (computes s_v)
    k_agggemm<true><<<FB, 256, 0, stream>>>(PqA, dis, row_ptr, edges,
                                            cvec + 0, dvec + 0, sarr, Wp + 4096, PhB);
    // layer 2 fused: agg(PhB) -> per-wave gemm -> PhA
    k_agggemm<false><<<FB, 256, 0, stream>>>(PqB, dis, row_ptr, edges,
                                             cvec + 64, dvec + 64, sarr, Wp + 8192, PhA);
    // layer 3: agg(PhA) -> Hh (12500 blocks, 1 node/wave)
    k_agg3<<<NN / 4, 256, 0, stream>>>(PqA, dis, row_ptr, edges,
                                       cvec + 128, dvec + 128, sarr, Hh);
    k_colsum<<<256, 256, 0, stream>>>(Hh, colsum);
    k_out<<<1, 64, 0, stream>>>(colsum, out_w, out_b, out);
}